// Round 1
// baseline (4703.972 us; speedup 1.0000x reference)
//
#include <hip/hip_runtime.h>
#include <cstdint>

#define D_MODEL 768
#define NHEAD 12
#define DK 64
#define BATCH 2
#define SEQ 4096
#define MTOT (BATCH * SEQ)  // 8192

// C[M x 768] = A[M x 768] @ W^T[768 x 768] + bias
// MODE 0: C row-major [M][768]
// MODE 1: C in [B, H, S, DK] head layout; head = blockIdx.x (N-tile == one head)
template <int MODE>
__global__ __launch_bounds__(256) void gemm_xwT(const float* __restrict__ A,
                                                const float* __restrict__ W,
                                                const float* __restrict__ bias,
                                                float* __restrict__ C) {
    __shared__ float As[16][68];  // k-major, padded: row stride 272B (16B aligned, bank stride 4)
    __shared__ float Ws[16][68];
    const int tx = threadIdx.x & 15;
    const int ty = threadIdx.x >> 4;
    const int n0 = blockIdx.x * 64;
    const int m0 = blockIdx.y * 64;
    const int lrow = threadIdx.x >> 2;        // 0..63
    const int lk4 = (threadIdx.x & 3) * 4;    // 0,4,8,12
    const float* Aptr = A + (size_t)(m0 + lrow) * D_MODEL + lk4;
    const float* Wptr = W + (size_t)(n0 + lrow) * D_MODEL + lk4;

    float4 acc[4];
#pragma unroll
    for (int i = 0; i < 4; ++i) acc[i] = make_float4(0.f, 0.f, 0.f, 0.f);

    for (int k0 = 0; k0 < D_MODEL; k0 += 16) {
        float4 av = *(const float4*)(Aptr + k0);
        float4 wv = *(const float4*)(Wptr + k0);
        As[lk4 + 0][lrow] = av.x;
        As[lk4 + 1][lrow] = av.y;
        As[lk4 + 2][lrow] = av.z;
        As[lk4 + 3][lrow] = av.w;
        Ws[lk4 + 0][lrow] = wv.x;
        Ws[lk4 + 1][lrow] = wv.y;
        Ws[lk4 + 2][lrow] = wv.z;
        Ws[lk4 + 3][lrow] = wv.w;
        __syncthreads();
#pragma unroll
        for (int kk = 0; kk < 16; ++kk) {
            float4 xa = *(const float4*)&As[kk][ty * 4];  // 4 m-rows
            float4 wb = *(const float4*)&Ws[kk][tx * 4];  // 4 n-cols
            acc[0].x += xa.x * wb.x; acc[0].y += xa.x * wb.y; acc[0].z += xa.x * wb.z; acc[0].w += xa.x * wb.w;
            acc[1].x += xa.y * wb.x; acc[1].y += xa.y * wb.y; acc[1].z += xa.y * wb.z; acc[1].w += xa.y * wb.w;
            acc[2].x += xa.z * wb.x; acc[2].y += xa.z * wb.y; acc[2].z += xa.z * wb.z; acc[2].w += xa.z * wb.w;
            acc[3].x += xa.w * wb.x; acc[3].y += xa.w * wb.y; acc[3].z += xa.w * wb.z; acc[3].w += xa.w * wb.w;
        }
        __syncthreads();
    }

    float4 bv = *(const float4*)&bias[n0 + tx * 4];
#pragma unroll
    for (int i = 0; i < 4; ++i) {
        const int m = m0 + ty * 4 + i;
        float4 r;
        r.x = acc[i].x + bv.x;
        r.y = acc[i].y + bv.y;
        r.z = acc[i].z + bv.z;
        r.w = acc[i].w + bv.w;
        if (MODE == 0) {
            *(float4*)&C[(size_t)m * D_MODEL + n0 + tx * 4] = r;
        } else {
            const int b = m >> 12;          // m / SEQ
            const int s = m & (SEQ - 1);    // m % SEQ
            *(float4*)&C[(((size_t)b * NHEAD + blockIdx.x) * SEQ + s) * DK + tx * 4] = r;
        }
    }
}

// Flash attention, fp32. Q,K,V in [B,H,S,DK]; output AO in [B,S,D_MODEL] (heads concatenated).
// One block = 64 query rows of one (b,h). 256 threads, 4x4 microtile per thread.
__global__ __launch_bounds__(256) void flash_attn(const float* __restrict__ Q,
                                                  const float* __restrict__ K,
                                                  const float* __restrict__ V,
                                                  float* __restrict__ AO) {
    __shared__ float Qs[64][68];
    __shared__ float KPs[64][68];  // holds K tile, then reused for P tile
    __shared__ float Vs[64][68];
    const int tx = threadIdx.x & 15;
    const int ty = threadIdx.x >> 4;
    const int bh = blockIdx.y;  // 0..23
    const int q0 = blockIdx.x * 64;
    const float* Qp = Q + (size_t)bh * SEQ * DK;
    const float* Kp = K + (size_t)bh * SEQ * DK;
    const float* Vp = V + (size_t)bh * SEQ * DK;

#pragma unroll
    for (int i = 0; i < 4; ++i) {
        const int f = threadIdx.x + i * 256;
        const int row = f >> 4;
        const int c4 = (f & 15) * 4;
        *(float4*)&Qs[row][c4] = *(const float4*)&Qp[(size_t)(q0 + row) * DK + c4];
    }

    float4 oacc[4];
    float m_r[4], l_r[4];
#pragma unroll
    for (int i = 0; i < 4; ++i) {
        oacc[i] = make_float4(0.f, 0.f, 0.f, 0.f);
        m_r[i] = -1e30f;
        l_r[i] = 0.f;
    }

    for (int kt = 0; kt < SEQ / 64; ++kt) {
        __syncthreads();  // previous PV done; safe to overwrite K/V (also pre-Q first iter)
#pragma unroll
        for (int i = 0; i < 4; ++i) {
            const int f = threadIdx.x + i * 256;
            const int row = f >> 4;
            const int c4 = (f & 15) * 4;
            *(float4*)&KPs[row][c4] = *(const float4*)&Kp[(size_t)(kt * 64 + row) * DK + c4];
            *(float4*)&Vs[row][c4] = *(const float4*)&Vp[(size_t)(kt * 64 + row) * DK + c4];
        }
        __syncthreads();

        // S = Q K^T for this tile: thread owns rows ty*4+i, cols tx*4+j
        float4 sr[4];
#pragma unroll
        for (int i = 0; i < 4; ++i) sr[i] = make_float4(0.f, 0.f, 0.f, 0.f);
#pragma unroll
        for (int d4 = 0; d4 < 16; ++d4) {
            float4 kv0 = *(const float4*)&KPs[tx * 4 + 0][d4 * 4];
            float4 kv1 = *(const float4*)&KPs[tx * 4 + 1][d4 * 4];
            float4 kv2 = *(const float4*)&KPs[tx * 4 + 2][d4 * 4];
            float4 kv3 = *(const float4*)&KPs[tx * 4 + 3][d4 * 4];
#pragma unroll
            for (int i = 0; i < 4; ++i) {
                float4 qv = *(const float4*)&Qs[ty * 4 + i][d4 * 4];
                sr[i].x += qv.x * kv0.x + qv.y * kv0.y + qv.z * kv0.z + qv.w * kv0.w;
                sr[i].y += qv.x * kv1.x + qv.y * kv1.y + qv.z * kv1.z + qv.w * kv1.w;
                sr[i].z += qv.x * kv2.x + qv.y * kv2.y + qv.z * kv2.z + qv.w * kv2.w;
                sr[i].w += qv.x * kv3.x + qv.y * kv3.y + qv.z * kv3.z + qv.w * kv3.w;
            }
        }
        __syncthreads();  // all threads done reading K tile; KPs can become P

        // online softmax per row; rows are owned by the 16 lanes sharing ty (lanes differ in low 4 bits)
#pragma unroll
        for (int i = 0; i < 4; ++i) {
            float4 s4 = sr[i];
            s4.x *= 0.125f; s4.y *= 0.125f; s4.z *= 0.125f; s4.w *= 0.125f;
            float mx = fmaxf(fmaxf(s4.x, s4.y), fmaxf(s4.z, s4.w));
#pragma unroll
            for (int off = 1; off < 16; off <<= 1) mx = fmaxf(mx, __shfl_xor(mx, off));
            const float mn = fmaxf(m_r[i], mx);
            const float corr = __expf(m_r[i] - mn);
            m_r[i] = mn;
            s4.x = __expf(s4.x - mn);
            s4.y = __expf(s4.y - mn);
            s4.z = __expf(s4.z - mn);
            s4.w = __expf(s4.w - mn);
            float rs = s4.x + s4.y + s4.z + s4.w;
#pragma unroll
            for (int off = 1; off < 16; off <<= 1) rs += __shfl_xor(rs, off);
            l_r[i] = l_r[i] * corr + rs;
            oacc[i].x *= corr; oacc[i].y *= corr; oacc[i].z *= corr; oacc[i].w *= corr;
            *(float4*)&KPs[ty * 4 + i][tx * 4] = s4;  // P tile
        }
        __syncthreads();  // P visible

        // O += P V : dot over key dim c; thread owns rows ty*4+i, d-cols tx*4+j
#pragma unroll
        for (int c4 = 0; c4 < 16; ++c4) {
            float4 vb0 = *(const float4*)&Vs[c4 * 4 + 0][tx * 4];
            float4 vb1 = *(const float4*)&Vs[c4 * 4 + 1][tx * 4];
            float4 vb2 = *(const float4*)&Vs[c4 * 4 + 2][tx * 4];
            float4 vb3 = *(const float4*)&Vs[c4 * 4 + 3][tx * 4];
#pragma unroll
            for (int i = 0; i < 4; ++i) {
                float4 pa = *(const float4*)&KPs[ty * 4 + i][c4 * 4];
                oacc[i].x += pa.x * vb0.x + pa.y * vb1.x + pa.z * vb2.x + pa.w * vb3.x;
                oacc[i].y += pa.x * vb0.y + pa.y * vb1.y + pa.z * vb2.y + pa.w * vb3.y;
                oacc[i].z += pa.x * vb0.z + pa.y * vb1.z + pa.z * vb2.z + pa.w * vb3.z;
                oacc[i].w += pa.x * vb0.w + pa.y * vb1.w + pa.z * vb2.w + pa.w * vb3.w;
            }
        }
    }

    const int b = bh / NHEAD;
    const int h = bh % NHEAD;
#pragma unroll
    for (int i = 0; i < 4; ++i) {
        const float inv = 1.0f / l_r[i];
        float4 r = make_float4(oacc[i].x * inv, oacc[i].y * inv, oacc[i].z * inv, oacc[i].w * inv);
        const int srow = q0 + ty * 4 + i;
        *(float4*)&AO[((size_t)b * SEQ + srow) * D_MODEL + h * DK + tx * 4] = r;
    }
}

extern "C" void kernel_launch(void* const* d_in, const int* in_sizes, int n_in,
                              void* d_out, int out_size, void* d_ws, size_t ws_size,
                              hipStream_t stream) {
    const float* q_in = (const float*)d_in[0];
    const float* k_in = (const float*)d_in[1];
    const float* v_in = (const float*)d_in[2];
    const float* Wq = (const float*)d_in[3];
    const float* bq = (const float*)d_in[4];
    const float* Wk = (const float*)d_in[5];
    const float* bk = (const float*)d_in[6];
    const float* Wv = (const float*)d_in[7];
    const float* bv = (const float*)d_in[8];
    const float* Wo = (const float*)d_in[9];
    const float* bo = (const float*)d_in[10];
    float* out = (float*)d_out;

    const size_t per = (size_t)BATCH * NHEAD * SEQ * DK;  // 6291456 floats
    float* qws = (float*)d_ws;
    float* kws = qws + per;
    float* vws = kws + per;
    float* aws = vws + per;  // [B, S, D_MODEL]
    // total ws use: 4 * 25165824 B = 96 MB

    dim3 blk(256);
    dim3 gproj(D_MODEL / 64, MTOT / 64);  // (12, 128)
    hipLaunchKernelGGL((gemm_xwT<1>), gproj, blk, 0, stream, q_in, Wq, bq, qws);
    hipLaunchKernelGGL((gemm_xwT<1>), gproj, blk, 0, stream, k_in, Wk, bk, kws);
    hipLaunchKernelGGL((gemm_xwT<1>), gproj, blk, 0, stream, v_in, Wv, bv, vws);

    dim3 gattn(SEQ / 64, BATCH * NHEAD);  // (64, 24)
    hipLaunchKernelGGL(flash_attn, gattn, blk, 0, stream, qws, kws, vws, aws);

    hipLaunchKernelGGL((gemm_xwT<0>), gproj, blk, 0, stream, aws, Wo, bo, out);
}

// Round 3
// 1069.072 us; speedup vs baseline: 4.4000x; 4.4000x over previous
//
#include <hip/hip_runtime.h>
#include <cstdint>

#define D_MODEL 768
#define NHEAD 12
#define DK 64
#define BATCH 2
#define SEQ 4096
#define MTOT (BATCH * SEQ)  // 8192

typedef __attribute__((ext_vector_type(8))) short bf16x8;   // 8 bf16 in 4 VGPRs
typedef __attribute__((ext_vector_type(4))) float f32x4;    // MFMA accumulator

typedef unsigned short ushort_t;
typedef unsigned int uint_t;

__device__ __forceinline__ ushort_t f2bf(float f) {
    uint_t u = __float_as_uint(f);
    u = u + 0x7fffu + ((u >> 16) & 1u);  // RNE
    return (ushort_t)(u >> 16);
}
__device__ __forceinline__ float bf2f(ushort_t h) {
    return __uint_as_float(((uint_t)h) << 16);
}

// XOR-swizzled byte offset inside a 64-row x 128B tile (row-major, 128B rows)
__device__ __forceinline__ int swz(int row, int col_bf16) {
    return (row * 128 + col_bf16 * 2) ^ ((row & 7) << 4);
}

// ============ projection GEMM: C[M x 768] = A[M x 768] @ W^T + bias ============
// MODE 0: fp32 row-major C [M][768]
// MODE 1: bf16 hi+lo, head layout [B,H,S,DK]   (Q, K)
// MODE 2: bf16 hi only, head layout            (V)
template <int MODE>
__global__ __launch_bounds__(256) void gemm_xwT(const float* __restrict__ A,
                                                const float* __restrict__ W,
                                                const float* __restrict__ bias,
                                                float* __restrict__ C,
                                                ushort_t* __restrict__ Chi,
                                                ushort_t* __restrict__ Clo) {
    __shared__ float As[16][68];
    __shared__ float Ws[16][68];
    const int tx = threadIdx.x & 15;
    const int ty = threadIdx.x >> 4;
    const int n0 = blockIdx.x * 64;
    const int m0 = blockIdx.y * 64;
    const int lrow = threadIdx.x >> 2;
    const int lk4 = (threadIdx.x & 3) * 4;
    const float* Aptr = A + (size_t)(m0 + lrow) * D_MODEL + lk4;
    const float* Wptr = W + (size_t)(n0 + lrow) * D_MODEL + lk4;

    float4 acc[4];
#pragma unroll
    for (int i = 0; i < 4; ++i) acc[i] = make_float4(0.f, 0.f, 0.f, 0.f);

    for (int k0 = 0; k0 < D_MODEL; k0 += 16) {
        float4 av = *(const float4*)(Aptr + k0);
        float4 wv = *(const float4*)(Wptr + k0);
        As[lk4 + 0][lrow] = av.x; As[lk4 + 1][lrow] = av.y;
        As[lk4 + 2][lrow] = av.z; As[lk4 + 3][lrow] = av.w;
        Ws[lk4 + 0][lrow] = wv.x; Ws[lk4 + 1][lrow] = wv.y;
        Ws[lk4 + 2][lrow] = wv.z; Ws[lk4 + 3][lrow] = wv.w;
        __syncthreads();
#pragma unroll
        for (int kk = 0; kk < 16; ++kk) {
            float4 xa = *(const float4*)&As[kk][ty * 4];
            float4 wb = *(const float4*)&Ws[kk][tx * 4];
            acc[0].x += xa.x * wb.x; acc[0].y += xa.x * wb.y; acc[0].z += xa.x * wb.z; acc[0].w += xa.x * wb.w;
            acc[1].x += xa.y * wb.x; acc[1].y += xa.y * wb.y; acc[1].z += xa.y * wb.z; acc[1].w += xa.y * wb.w;
            acc[2].x += xa.z * wb.x; acc[2].y += xa.z * wb.y; acc[2].z += xa.z * wb.z; acc[2].w += xa.z * wb.w;
            acc[3].x += xa.w * wb.x; acc[3].y += xa.w * wb.y; acc[3].z += xa.w * wb.z; acc[3].w += xa.w * wb.w;
        }
        __syncthreads();
    }

    float4 bv = *(const float4*)&bias[n0 + tx * 4];
#pragma unroll
    for (int i = 0; i < 4; ++i) {
        const int m = m0 + ty * 4 + i;
        float4 r;
        r.x = acc[i].x + bv.x; r.y = acc[i].y + bv.y;
        r.z = acc[i].z + bv.z; r.w = acc[i].w + bv.w;
        if (MODE == 0) {
            *(float4*)&C[(size_t)m * D_MODEL + n0 + tx * 4] = r;
        } else {
            const int b = m >> 12;
            const int s = m & (SEQ - 1);
            const size_t idx = (((size_t)b * NHEAD + blockIdx.x) * SEQ + s) * DK + tx * 4;
            ushort4 h;
            h.x = f2bf(r.x); h.y = f2bf(r.y); h.z = f2bf(r.z); h.w = f2bf(r.w);
            *(ushort4*)&Chi[idx] = h;
            if (MODE == 1) {
                ushort4 l;
                l.x = f2bf(r.x - bf2f(h.x));
                l.y = f2bf(r.y - bf2f(h.y));
                l.z = f2bf(r.z - bf2f(h.z));
                l.w = f2bf(r.w - bf2f(h.w));
                *(ushort4*)&Clo[idx] = l;
            }
        }
    }
}

// ============ MFMA flash attention ============
// Q,K: split bf16 (hi+lo); V: bf16 hi. All in [B,H,S,DK].
// Block: 256 thr = 4 waves; wave w owns q-rows [w*16, w*16+16). KBLK=64.
// AO: fp32 [B,S,D_MODEL]
__global__ __launch_bounds__(256) void flash_mfma(const ushort_t* __restrict__ qh_g,
                                                  const ushort_t* __restrict__ ql_g,
                                                  const ushort_t* __restrict__ kh_g,
                                                  const ushort_t* __restrict__ kl_g,
                                                  const ushort_t* __restrict__ vh_g,
                                                  float* __restrict__ AO) {
    __shared__ __align__(16) char lds[49152];
    constexpr int QHI = 0, QLO = 8192, KHI = 16384, KLO = 24576, VT = 32768, PB = 40960;

    const int tid = threadIdx.x;
    const int lane = tid & 63;
    const int w = tid >> 6;
    const int li = lane & 15;
    const int g = lane >> 4;
    const int bh = blockIdx.y;
    const int q0 = blockIdx.x * 64;

    const ushort_t* qhp = qh_g + (size_t)bh * SEQ * DK;
    const ushort_t* qlp = ql_g + (size_t)bh * SEQ * DK;
    const ushort_t* khp = kh_g + (size_t)bh * SEQ * DK;
    const ushort_t* klp = kl_g + (size_t)bh * SEQ * DK;
    const ushort_t* vhp = vh_g + (size_t)bh * SEQ * DK;

    // ---- stage Q hi/lo (64x64 bf16 each), swizzled
    {
        const int row = tid >> 2;
        const int c0 = (tid & 3) * 16;
        const ushort_t* s0 = qhp + (size_t)(q0 + row) * DK + c0;
        const ushort_t* s1 = qlp + (size_t)(q0 + row) * DK + c0;
        bf16x8 a0 = *(const bf16x8*)s0;
        bf16x8 a1 = *(const bf16x8*)(s0 + 8);
        bf16x8 b0 = *(const bf16x8*)s1;
        bf16x8 b1 = *(const bf16x8*)(s1 + 8);
        *(bf16x8*)(lds + QHI + swz(row, c0)) = a0;
        *(bf16x8*)(lds + QHI + swz(row, c0 + 8)) = a1;
        *(bf16x8*)(lds + QLO + swz(row, c0)) = b0;
        *(bf16x8*)(lds + QLO + swz(row, c0 + 8)) = b1;
    }
    __syncthreads();

    // Q fragments: row = w*16 + li, cols ks*32 + g*8 (constant over the k-loop)
    bf16x8 qfh[2], qfl[2];
#pragma unroll
    for (int ks = 0; ks < 2; ++ks) {
        qfh[ks] = *(const bf16x8*)(lds + QHI + swz(w * 16 + li, ks * 32 + g * 8));
        qfl[ks] = *(const bf16x8*)(lds + QLO + swz(w * 16 + li, ks * 32 + g * 8));
    }

    f32x4 oacc[4];
    float m_r[4], l_r[4];
#pragma unroll
    for (int i = 0; i < 4; ++i) {
        oacc[i] = (f32x4){0.f, 0.f, 0.f, 0.f};
        m_r[i] = -1e30f;
        l_r[i] = 0.f;
    }

    for (int kt = 0; kt < SEQ / 64; ++kt) {
        __syncthreads();  // all waves done with previous K/V tiles
        // ---- stage K hi/lo (64x64 bf16, swizzled)
        {
            const int row = tid >> 2;
            const int c0 = (tid & 3) * 16;
            const ushort_t* s0 = khp + (size_t)(kt * 64 + row) * DK + c0;
            const ushort_t* s1 = klp + (size_t)(kt * 64 + row) * DK + c0;
            bf16x8 a0 = *(const bf16x8*)s0;
            bf16x8 a1 = *(const bf16x8*)(s0 + 8);
            bf16x8 b0 = *(const bf16x8*)s1;
            bf16x8 b1 = *(const bf16x8*)(s1 + 8);
            *(bf16x8*)(lds + KHI + swz(row, c0)) = a0;
            *(bf16x8*)(lds + KHI + swz(row, c0 + 8)) = a1;
            *(bf16x8*)(lds + KLO + swz(row, c0)) = b0;
            *(bf16x8*)(lds + KLO + swz(row, c0 + 8)) = b1;
        }
        // ---- stage V transposed: Vt[d][k], wave w covers k in [kt*64+w*16, +16), lane = d
        {
            const int d = lane;
            const int k0 = kt * 64 + w * 16;
            ushort_t vals[16];
#pragma unroll
            for (int j = 0; j < 16; ++j) vals[j] = vhp[(size_t)(k0 + j) * DK + d];
#pragma unroll
            for (int j4 = 0; j4 < 4; ++j4) {
                ushort4 u;
                u.x = vals[j4 * 4 + 0]; u.y = vals[j4 * 4 + 1];
                u.z = vals[j4 * 4 + 2]; u.w = vals[j4 * 4 + 3];
                *(ushort4*)(lds + VT + swz(d, w * 16 + j4 * 4)) = u;
            }
        }
        __syncthreads();  // K/V ready

        // ---- S = Q K^T (split bf16): S[q][kc] ; A=Q band, B=K^T
        f32x4 sacc[4];
#pragma unroll
        for (int t = 0; t < 4; ++t) sacc[t] = (f32x4){0.f, 0.f, 0.f, 0.f};
#pragma unroll
        for (int t = 0; t < 4; ++t) {
#pragma unroll
            for (int ks = 0; ks < 2; ++ks) {
                bf16x8 kfh = *(const bf16x8*)(lds + KHI + swz(t * 16 + li, ks * 32 + g * 8));
                bf16x8 kfl = *(const bf16x8*)(lds + KLO + swz(t * 16 + li, ks * 32 + g * 8));
                sacc[t] = __builtin_amdgcn_mfma_f32_16x16x32_bf16(qfl[ks], kfh, sacc[t], 0, 0, 0);
                sacc[t] = __builtin_amdgcn_mfma_f32_16x16x32_bf16(qfh[ks], kfl, sacc[t], 0, 0, 0);
                sacc[t] = __builtin_amdgcn_mfma_f32_16x16x32_bf16(qfh[ks], kfh, sacc[t], 0, 0, 0);
            }
        }

        // ---- online softmax; lane holds S[row=g*4+r][col=t*16+li] in sacc[t][r]
        const int pb = PB + w * 2048;
#pragma unroll
        for (int r = 0; r < 4; ++r) {
            float s0 = sacc[0][r] * 0.125f;
            float s1 = sacc[1][r] * 0.125f;
            float s2 = sacc[2][r] * 0.125f;
            float s3 = sacc[3][r] * 0.125f;
            float mx = fmaxf(fmaxf(s0, s1), fmaxf(s2, s3));
            mx = fmaxf(mx, __shfl_xor(mx, 1));
            mx = fmaxf(mx, __shfl_xor(mx, 2));
            mx = fmaxf(mx, __shfl_xor(mx, 4));
            mx = fmaxf(mx, __shfl_xor(mx, 8));
            const float mn = fmaxf(m_r[r], mx);
            const float corr = __expf(m_r[r] - mn);
            m_r[r] = mn;
            float p0 = __expf(s0 - mn);
            float p1 = __expf(s1 - mn);
            float p2 = __expf(s2 - mn);
            float p3 = __expf(s3 - mn);
            float rs = (p0 + p1) + (p2 + p3);
            rs += __shfl_xor(rs, 1);
            rs += __shfl_xor(rs, 2);
            rs += __shfl_xor(rs, 4);
            rs += __shfl_xor(rs, 8);
            l_r[r] = l_r[r] * corr + rs;
            oacc[0][r] *= corr; oacc[1][r] *= corr;
            oacc[2][r] *= corr; oacc[3][r] *= corr;
            const int prow = g * 4 + r;
            *(ushort_t*)(lds + pb + swz(prow, 0 * 16 + li)) = f2bf(p0);
            *(ushort_t*)(lds + pb + swz(prow, 1 * 16 + li)) = f2bf(p1);
            *(ushort_t*)(lds + pb + swz(prow, 2 * 16 + li)) = f2bf(p2);
            *(ushort_t*)(lds + pb + swz(prow, 3 * 16 + li)) = f2bf(p3);
        }

        // ---- O += P V   (A = P band [16x64], B = V [64k x 64d] via Vt)
        bf16x8 pa[2];
#pragma unroll
        for (int ks = 0; ks < 2; ++ks)
            pa[ks] = *(const bf16x8*)(lds + pb + swz(li, ks * 32 + g * 8));
#pragma unroll
        for (int dt = 0; dt < 4; ++dt) {
#pragma unroll
            for (int ks = 0; ks < 2; ++ks) {
                bf16x8 vf = *(const bf16x8*)(lds + VT + swz(dt * 16 + li, ks * 32 + g * 8));
                oacc[dt] = __builtin_amdgcn_mfma_f32_16x16x32_bf16(pa[ks], vf, oacc[dt], 0, 0, 0);
            }
        }
    }

    // ---- epilogue
    float inv[4];
#pragma unroll
    for (int r = 0; r < 4; ++r) inv[r] = 1.0f / l_r[r];
    const int b = bh / NHEAD;
    const int h = bh % NHEAD;
#pragma unroll
    for (int dt = 0; dt < 4; ++dt) {
#pragma unroll
        for (int r = 0; r < 4; ++r) {
            const int srow = q0 + w * 16 + g * 4 + r;
            AO[((size_t)b * SEQ + srow) * D_MODEL + h * DK + dt * 16 + li] = oacc[dt][r] * inv[r];
        }
    }
}

extern "C" void kernel_launch(void* const* d_in, const int* in_sizes, int n_in,
                              void* d_out, int out_size, void* d_ws, size_t ws_size,
                              hipStream_t stream) {
    const float* q_in = (const float*)d_in[0];
    const float* k_in = (const float*)d_in[1];
    const float* v_in = (const float*)d_in[2];
    const float* Wq = (const float*)d_in[3];
    const float* bq = (const float*)d_in[4];
    const float* Wk = (const float*)d_in[5];
    const float* bk = (const float*)d_in[6];
    const float* Wv = (const float*)d_in[7];
    const float* bv = (const float*)d_in[8];
    const float* Wo = (const float*)d_in[9];
    const float* bo = (const float*)d_in[10];
    float* out = (float*)d_out;

    const size_t per = (size_t)BATCH * NHEAD * SEQ * DK;  // 6,291,456
    ushort_t* qh = (ushort_t*)d_ws;
    ushort_t* ql = qh + per;
    ushort_t* kh = ql + per;
    ushort_t* kl = kh + per;
    ushort_t* vh = kl + per;
    float* aws = (float*)(vh + per);  // [B,S,D_MODEL] fp32, starts at byte 5*per*2

    dim3 blk(256);
    dim3 gproj(D_MODEL / 64, MTOT / 64);  // (12, 128)
    hipLaunchKernelGGL((gemm_xwT<1>), gproj, blk, 0, stream, q_in, Wq, bq, nullptr, qh, ql);
    hipLaunchKernelGGL((gemm_xwT<1>), gproj, blk, 0, stream, k_in, Wk, bk, nullptr, kh, kl);
    hipLaunchKernelGGL((gemm_xwT<2>), gproj, blk, 0, stream, v_in, Wv, bv, nullptr, vh, nullptr);

    dim3 gattn(SEQ / 64, BATCH * NHEAD);  // (64, 24)
    hipLaunchKernelGGL(flash_mfma, gattn, blk, 0, stream, qh, ql, kh, kl, vh, aws);

    hipLaunchKernelGGL((gemm_xwT<0>), gproj, blk, 0, stream, aws, Wo, bo, out, nullptr, nullptr);
}

// Round 4
// 793.413 us; speedup vs baseline: 5.9288x; 1.3474x over previous
//
#include <hip/hip_runtime.h>
#include <cstdint>

#define D_MODEL 768
#define NHEAD 12
#define DK 64
#define BATCH 2
#define SEQ 4096
#define MTOT (BATCH * SEQ)  // 8192

typedef __attribute__((ext_vector_type(8))) short bf16x8;      // 8 bf16 = 4 VGPRs
typedef __attribute__((ext_vector_type(8))) _Float16 f16x8;    // 8 fp16 = 4 VGPRs
typedef __attribute__((ext_vector_type(4))) float f32x4;

typedef unsigned short ushort_t;
typedef unsigned int uint_t;

#define SCALE_LOG2E 0.18033688011112042f  // 0.125 * log2(e)

__device__ __forceinline__ ushort_t f2bf(float f) {
    uint_t u = __float_as_uint(f);
    u = u + 0x7fffu + ((u >> 16) & 1u);  // RNE
    return (ushort_t)(u >> 16);
}
__device__ __forceinline__ float bf2f(ushort_t h) {
    return __uint_as_float(((uint_t)h) << 16);
}
#define EXP2(d, s) asm("v_exp_f32 %0, %1" : "=v"(d) : "v"(s))

// XOR-swizzled byte offset inside a row-major tile with 128B rows (64 bf16/f16)
__device__ __forceinline__ int swz(int row, int col_e) {
    return (row * 128 + col_e * 2) ^ ((row & 7) << 4);
}

// ================= fp16 MFMA projection GEMM =================
// C[m][n] = sum_k A[m][k] * W[n][k] + bias[n], computed in fp16 (fp32 acc).
// BM=128, BN=64 (=1 head), BK=64. 256 thr = 4 waves in 2x2.
// EPI 1: bf16 hi/lo, head layout [B,H,S,DK], scaled by alpha (Q: alpha=SCALE_LOG2E, K: 1)
// EPI 2: bf16 hi only, head layout (V)
template <int EPI>
__global__ __launch_bounds__(256) void gemm_f16(const float* __restrict__ A,
                                                const float* __restrict__ W,
                                                const float* __restrict__ bias,
                                                ushort_t* __restrict__ Chi,
                                                ushort_t* __restrict__ Clo,
                                                float alpha) {
    __shared__ __align__(16) char lds[24576];  // A-tile 16KB @0, W-tile 8KB @16384
    const int tid = threadIdx.x;
    const int lane = tid & 63;
    const int w = tid >> 6;
    const int li = lane & 15;
    const int g = lane >> 4;
    const int wr = w >> 1, wc = w & 1;
    const int m0 = blockIdx.y * 128;
    const int n0 = blockIdx.x * 64;

    f32x4 acc[4][2];
#pragma unroll
    for (int fr = 0; fr < 4; ++fr)
#pragma unroll
        for (int fc = 0; fc < 2; ++fc) acc[fr][fc] = (f32x4){0.f, 0.f, 0.f, 0.f};

    for (int k0 = 0; k0 < D_MODEL; k0 += 64) {
        __syncthreads();
        // stage A-tile 128x64 fp32 -> f16 (1024 chunks of 8)
#pragma unroll
        for (int i = 0; i < 4; ++i) {
            const int c = tid + i * 256;
            const int row = c >> 3;
            const int c8 = (c & 7) * 8;
            const float* src = A + (size_t)(m0 + row) * D_MODEL + k0 + c8;
            float4 f0 = *(const float4*)src;
            float4 f1 = *(const float4*)(src + 4);
            f16x8 h;
            h[0] = (_Float16)f0.x; h[1] = (_Float16)f0.y; h[2] = (_Float16)f0.z; h[3] = (_Float16)f0.w;
            h[4] = (_Float16)f1.x; h[5] = (_Float16)f1.y; h[6] = (_Float16)f1.z; h[7] = (_Float16)f1.w;
            *(f16x8*)(lds + swz(row, c8)) = h;
        }
        // stage W-tile 64x64 (512 chunks)
#pragma unroll
        for (int i = 0; i < 2; ++i) {
            const int c = tid + i * 256;
            const int row = c >> 3;
            const int c8 = (c & 7) * 8;
            const float* src = W + (size_t)(n0 + row) * D_MODEL + k0 + c8;
            float4 f0 = *(const float4*)src;
            float4 f1 = *(const float4*)(src + 4);
            f16x8 h;
            h[0] = (_Float16)f0.x; h[1] = (_Float16)f0.y; h[2] = (_Float16)f0.z; h[3] = (_Float16)f0.w;
            h[4] = (_Float16)f1.x; h[5] = (_Float16)f1.y; h[6] = (_Float16)f1.z; h[7] = (_Float16)f1.w;
            *(f16x8*)(lds + 16384 + swz(row, c8)) = h;
        }
        __syncthreads();
#pragma unroll
        for (int ks = 0; ks < 2; ++ks) {
            f16x8 ar[4], br[2];
#pragma unroll
            for (int fr = 0; fr < 4; ++fr)
                ar[fr] = *(const f16x8*)(lds + swz(wr * 64 + fr * 16 + li, ks * 32 + g * 8));
#pragma unroll
            for (int fc = 0; fc < 2; ++fc)
                br[fc] = *(const f16x8*)(lds + 16384 + swz(wc * 32 + fc * 16 + li, ks * 32 + g * 8));
#pragma unroll
            for (int fr = 0; fr < 4; ++fr)
#pragma unroll
                for (int fc = 0; fc < 2; ++fc)
                    acc[fr][fc] = __builtin_amdgcn_mfma_f32_16x16x32_f16(ar[fr], br[fc], acc[fr][fc], 0, 0, 0);
        }
    }

    // epilogue: head = blockIdx.x; row m -> (b, s)
#pragma unroll
    for (int fr = 0; fr < 4; ++fr)
#pragma unroll
        for (int fc = 0; fc < 2; ++fc)
#pragma unroll
            for (int r = 0; r < 4; ++r) {
                const int m = m0 + wr * 64 + fr * 16 + g * 4 + r;
                const int d = wc * 32 + fc * 16 + li;
                float val = acc[fr][fc][r] + bias[n0 + d];
                val *= alpha;
                const int b = m >> 12;
                const int s = m & (SEQ - 1);
                const size_t idx = (((size_t)b * NHEAD + blockIdx.x) * SEQ + s) * DK + d;
                ushort_t hi = f2bf(val);
                Chi[idx] = hi;
                if (EPI == 1) Clo[idx] = f2bf(val - bf2f(hi));
            }
}

// ================= split-bf16 out-projection =================
// out[m][n] = sum_k (Ah+Al)[m][k] * (Wh+Wl)[n][k] + bias[n]  (3-term split product)
__global__ __launch_bounds__(256) void gemm_osplit(const ushort_t* __restrict__ Ah,
                                                   const ushort_t* __restrict__ Al,
                                                   const float* __restrict__ W,
                                                   const float* __restrict__ bias,
                                                   float* __restrict__ out) {
    __shared__ __align__(16) char lds[49152];  // AH@0 16K, AL@16384 16K, WH@32768 8K, WL@40960 8K
    const int tid = threadIdx.x;
    const int lane = tid & 63;
    const int w = tid >> 6;
    const int li = lane & 15;
    const int g = lane >> 4;
    const int wr = w >> 1, wc = w & 1;
    const int m0 = blockIdx.y * 128;
    const int n0 = blockIdx.x * 64;

    f32x4 acc[4][2];
#pragma unroll
    for (int fr = 0; fr < 4; ++fr)
#pragma unroll
        for (int fc = 0; fc < 2; ++fc) acc[fr][fc] = (f32x4){0.f, 0.f, 0.f, 0.f};

    for (int k0 = 0; k0 < D_MODEL; k0 += 64) {
        __syncthreads();
#pragma unroll
        for (int i = 0; i < 4; ++i) {
            const int c = tid + i * 256;
            const int row = c >> 3;
            const int c8 = (c & 7) * 8;
            const size_t src = (size_t)(m0 + row) * D_MODEL + k0 + c8;
            *(bf16x8*)(lds + swz(row, c8)) = *(const bf16x8*)(Ah + src);
            *(bf16x8*)(lds + 16384 + swz(row, c8)) = *(const bf16x8*)(Al + src);
        }
#pragma unroll
        for (int i = 0; i < 2; ++i) {
            const int c = tid + i * 256;
            const int row = c >> 3;
            const int c8 = (c & 7) * 8;
            const float* src = W + (size_t)(n0 + row) * D_MODEL + k0 + c8;
            float4 f0 = *(const float4*)src;
            float4 f1 = *(const float4*)(src + 4);
            ushort_t h[8], l[8];
            float v[8] = {f0.x, f0.y, f0.z, f0.w, f1.x, f1.y, f1.z, f1.w};
#pragma unroll
            for (int j = 0; j < 8; ++j) {
                h[j] = f2bf(v[j]);
                l[j] = f2bf(v[j] - bf2f(h[j]));
            }
            *(bf16x8*)(lds + 32768 + swz(row, c8)) = *(bf16x8*)h;
            *(bf16x8*)(lds + 40960 + swz(row, c8)) = *(bf16x8*)l;
        }
        __syncthreads();
#pragma unroll
        for (int ks = 0; ks < 2; ++ks) {
            bf16x8 arh[4], arl[4], brh[2], brl[2];
#pragma unroll
            for (int fr = 0; fr < 4; ++fr) {
                arh[fr] = *(const bf16x8*)(lds + swz(wr * 64 + fr * 16 + li, ks * 32 + g * 8));
                arl[fr] = *(const bf16x8*)(lds + 16384 + swz(wr * 64 + fr * 16 + li, ks * 32 + g * 8));
            }
#pragma unroll
            for (int fc = 0; fc < 2; ++fc) {
                brh[fc] = *(const bf16x8*)(lds + 32768 + swz(wc * 32 + fc * 16 + li, ks * 32 + g * 8));
                brl[fc] = *(const bf16x8*)(lds + 40960 + swz(wc * 32 + fc * 16 + li, ks * 32 + g * 8));
            }
#pragma unroll
            for (int fr = 0; fr < 4; ++fr)
#pragma unroll
                for (int fc = 0; fc < 2; ++fc) {
                    acc[fr][fc] = __builtin_amdgcn_mfma_f32_16x16x32_bf16(arl[fr], brh[fc], acc[fr][fc], 0, 0, 0);
                    acc[fr][fc] = __builtin_amdgcn_mfma_f32_16x16x32_bf16(arh[fr], brl[fc], acc[fr][fc], 0, 0, 0);
                    acc[fr][fc] = __builtin_amdgcn_mfma_f32_16x16x32_bf16(arh[fr], brh[fc], acc[fr][fc], 0, 0, 0);
                }
        }
    }
#pragma unroll
    for (int fr = 0; fr < 4; ++fr)
#pragma unroll
        for (int fc = 0; fc < 2; ++fc)
#pragma unroll
            for (int r = 0; r < 4; ++r) {
                const int m = m0 + wr * 64 + fr * 16 + g * 4 + r;
                const int n = n0 + wc * 32 + fc * 16 + li;
                out[(size_t)m * D_MODEL + n] = acc[fr][fc][r] + bias[n];
            }
}

// ================= MFMA flash attention v2 =================
// QBLK=128 (Q frags in regs), KBLK=64, exp2-domain (scale folded into Q), defer-max.
// Writes attention output as bf16 hi/lo in [MTOT][768] row-major.
__global__ __launch_bounds__(256) void flash2(const ushort_t* __restrict__ qh_g,
                                              const ushort_t* __restrict__ ql_g,
                                              const ushort_t* __restrict__ kh_g,
                                              const ushort_t* __restrict__ kl_g,
                                              const ushort_t* __restrict__ vh_g,
                                              ushort_t* __restrict__ awh,
                                              ushort_t* __restrict__ awl) {
    __shared__ __align__(16) char lds[40960];
    constexpr int KHI = 0, KLO = 8192, VT = 16384, PB = 24576;  // PB + w*4096, 4KB/wave

    const int tid = threadIdx.x;
    const int lane = tid & 63;
    const int w = tid >> 6;
    const int li = lane & 15;
    const int g = lane >> 4;
    const int bh = blockIdx.y;
    const int q0 = blockIdx.x * 128;

    const ushort_t* qhp = qh_g + (size_t)bh * SEQ * DK;
    const ushort_t* qlp = ql_g + (size_t)bh * SEQ * DK;
    const ushort_t* khp = kh_g + (size_t)bh * SEQ * DK;
    const ushort_t* klp = kl_g + (size_t)bh * SEQ * DK;
    const ushort_t* vhp = vh_g + (size_t)bh * SEQ * DK;

    // Q fragments direct from global (once): rows q0 + w*32 + h*16 + li
    bf16x8 qfh[2][2], qfl[2][2];
#pragma unroll
    for (int h = 0; h < 2; ++h)
#pragma unroll
        for (int ks = 0; ks < 2; ++ks) {
            const size_t off = (size_t)(q0 + w * 32 + h * 16 + li) * DK + ks * 32 + g * 8;
            qfh[h][ks] = *(const bf16x8*)(qhp + off);
            qfl[h][ks] = *(const bf16x8*)(qlp + off);
        }

    f32x4 oacc[2][4];
    float m_r[8], l_r[8];
#pragma unroll
    for (int h = 0; h < 2; ++h)
#pragma unroll
        for (int dt = 0; dt < 4; ++dt) oacc[h][dt] = (f32x4){0.f, 0.f, 0.f, 0.f};
#pragma unroll
    for (int i = 0; i < 8; ++i) { m_r[i] = -1e30f; l_r[i] = 0.f; }

    for (int kt = 0; kt < SEQ / 64; ++kt) {
        __syncthreads();  // all waves done reading previous K/V
        // ---- stage K hi/lo (64x64, swizzled)
        {
            const int row = tid >> 2;
            const int c0 = (tid & 3) * 16;
            const ushort_t* s0 = khp + (size_t)(kt * 64 + row) * DK + c0;
            const ushort_t* s1 = klp + (size_t)(kt * 64 + row) * DK + c0;
            bf16x8 a0 = *(const bf16x8*)s0;
            bf16x8 a1 = *(const bf16x8*)(s0 + 8);
            bf16x8 b0 = *(const bf16x8*)s1;
            bf16x8 b1 = *(const bf16x8*)(s1 + 8);
            *(bf16x8*)(lds + KHI + swz(row, c0)) = a0;
            *(bf16x8*)(lds + KHI + swz(row, c0 + 8)) = a1;
            *(bf16x8*)(lds + KLO + swz(row, c0)) = b0;
            *(bf16x8*)(lds + KLO + swz(row, c0 + 8)) = b1;
        }
        // ---- stage V transposed Vt[d][k]
        {
            const int d = lane;
            const int k0 = kt * 64 + w * 16;
            ushort_t vals[16];
#pragma unroll
            for (int j = 0; j < 16; ++j) vals[j] = vhp[(size_t)(k0 + j) * DK + d];
#pragma unroll
            for (int j4 = 0; j4 < 4; ++j4) {
                ushort4 u;
                u.x = vals[j4 * 4 + 0]; u.y = vals[j4 * 4 + 1];
                u.z = vals[j4 * 4 + 2]; u.w = vals[j4 * 4 + 3];
                *(ushort4*)(lds + VT + swz(d, w * 16 + j4 * 4)) = u;
            }
        }
        __syncthreads();

        // ---- S = Q K^T, split bf16, log2-domain (scale pre-folded into Q)
        f32x4 sacc[2][4];
#pragma unroll
        for (int h = 0; h < 2; ++h)
#pragma unroll
            for (int t = 0; t < 4; ++t) sacc[h][t] = (f32x4){0.f, 0.f, 0.f, 0.f};
#pragma unroll
        for (int t = 0; t < 4; ++t)
#pragma unroll
            for (int ks = 0; ks < 2; ++ks) {
                bf16x8 kfh = *(const bf16x8*)(lds + KHI + swz(t * 16 + li, ks * 32 + g * 8));
                bf16x8 kfl = *(const bf16x8*)(lds + KLO + swz(t * 16 + li, ks * 32 + g * 8));
#pragma unroll
                for (int h = 0; h < 2; ++h) {
                    sacc[h][t] = __builtin_amdgcn_mfma_f32_16x16x32_bf16(qfl[h][ks], kfh, sacc[h][t], 0, 0, 0);
                    sacc[h][t] = __builtin_amdgcn_mfma_f32_16x16x32_bf16(qfh[h][ks], kfl, sacc[h][t], 0, 0, 0);
                    sacc[h][t] = __builtin_amdgcn_mfma_f32_16x16x32_bf16(qfh[h][ks], kfh, sacc[h][t], 0, 0, 0);
                }
            }

        // ---- online softmax (log2 domain), defer-max
        float pm[8];
#pragma unroll
        for (int h = 0; h < 2; ++h)
#pragma unroll
            for (int r = 0; r < 4; ++r) {
                float mx = fmaxf(fmaxf(sacc[h][0][r], sacc[h][1][r]),
                                 fmaxf(sacc[h][2][r], sacc[h][3][r]));
                mx = fmaxf(mx, __shfl_xor(mx, 1));
                mx = fmaxf(mx, __shfl_xor(mx, 2));
                mx = fmaxf(mx, __shfl_xor(mx, 4));
                mx = fmaxf(mx, __shfl_xor(mx, 8));
                pm[h * 4 + r] = mx;
            }
        bool need = false;
#pragma unroll
        for (int i = 0; i < 8; ++i) need = need || (pm[i] > m_r[i] + 8.0f);
        if (__any(need)) {
#pragma unroll
            for (int h = 0; h < 2; ++h)
#pragma unroll
                for (int r = 0; r < 4; ++r) {
                    const int i = h * 4 + r;
                    const float mn = fmaxf(m_r[i], pm[i]);
                    float corr;
                    float dd = m_r[i] - mn;
                    EXP2(corr, dd);
                    m_r[i] = mn;
                    l_r[i] *= corr;
#pragma unroll
                    for (int dt = 0; dt < 4; ++dt) oacc[h][dt][r] *= corr;
                }
        }
        const int pb = PB + w * 4096;
#pragma unroll
        for (int h = 0; h < 2; ++h)
#pragma unroll
            for (int r = 0; r < 4; ++r) {
                const int i = h * 4 + r;
                float p0, p1, p2, p3;
                float d0 = sacc[h][0][r] - m_r[i];
                float d1 = sacc[h][1][r] - m_r[i];
                float d2 = sacc[h][2][r] - m_r[i];
                float d3 = sacc[h][3][r] - m_r[i];
                EXP2(p0, d0); EXP2(p1, d1); EXP2(p2, d2); EXP2(p3, d3);
                float rs = (p0 + p1) + (p2 + p3);
                rs += __shfl_xor(rs, 1);
                rs += __shfl_xor(rs, 2);
                rs += __shfl_xor(rs, 4);
                rs += __shfl_xor(rs, 8);
                l_r[i] += rs;
                const int prow = h * 16 + g * 4 + r;
                *(ushort_t*)(lds + pb + swz(prow, 0 * 16 + li)) = f2bf(p0);
                *(ushort_t*)(lds + pb + swz(prow, 1 * 16 + li)) = f2bf(p1);
                *(ushort_t*)(lds + pb + swz(prow, 2 * 16 + li)) = f2bf(p2);
                *(ushort_t*)(lds + pb + swz(prow, 3 * 16 + li)) = f2bf(p3);
            }

        // ---- O += P V (wave-private P; same-wave LDS ordering via lgkmcnt)
        bf16x8 pa[2][2];
#pragma unroll
        for (int h = 0; h < 2; ++h)
#pragma unroll
            for (int ks = 0; ks < 2; ++ks)
                pa[h][ks] = *(const bf16x8*)(lds + pb + swz(h * 16 + li, ks * 32 + g * 8));
#pragma unroll
        for (int dt = 0; dt < 4; ++dt)
#pragma unroll
            for (int ks = 0; ks < 2; ++ks) {
                bf16x8 vf = *(const bf16x8*)(lds + VT + swz(dt * 16 + li, ks * 32 + g * 8));
#pragma unroll
                for (int h = 0; h < 2; ++h)
                    oacc[h][dt] = __builtin_amdgcn_mfma_f32_16x16x32_bf16(pa[h][ks], vf, oacc[h][dt], 0, 0, 0);
            }
    }

    // ---- epilogue: write bf16 hi/lo into [MTOT][768]
    float inv[8];
#pragma unroll
    for (int i = 0; i < 8; ++i) inv[i] = 1.0f / l_r[i];
    const int b = bh / NHEAD;
    const int hh = bh % NHEAD;
#pragma unroll
    for (int h = 0; h < 2; ++h)
#pragma unroll
        for (int dt = 0; dt < 4; ++dt)
#pragma unroll
            for (int r = 0; r < 4; ++r) {
                const float val = oacc[h][dt][r] * inv[h * 4 + r];
                const int srow = q0 + w * 32 + h * 16 + g * 4 + r;
                const size_t idx = ((size_t)b * SEQ + srow) * D_MODEL + hh * DK + dt * 16 + li;
                ushort_t hi = f2bf(val);
                awh[idx] = hi;
                awl[idx] = f2bf(val - bf2f(hi));
            }
}

extern "C" void kernel_launch(void* const* d_in, const int* in_sizes, int n_in,
                              void* d_out, int out_size, void* d_ws, size_t ws_size,
                              hipStream_t stream) {
    const float* q_in = (const float*)d_in[0];
    const float* k_in = (const float*)d_in[1];
    const float* v_in = (const float*)d_in[2];
    const float* Wq = (const float*)d_in[3];
    const float* bq = (const float*)d_in[4];
    const float* Wk = (const float*)d_in[5];
    const float* bk = (const float*)d_in[6];
    const float* Wv = (const float*)d_in[7];
    const float* bv = (const float*)d_in[8];
    const float* Wo = (const float*)d_in[9];
    const float* bo = (const float*)d_in[10];
    float* out = (float*)d_out;

    const size_t per = (size_t)BATCH * NHEAD * SEQ * DK;  // 6,291,456
    ushort_t* qh = (ushort_t*)d_ws;
    ushort_t* ql = qh + per;
    ushort_t* kh = ql + per;
    ushort_t* kl = kh + per;
    ushort_t* vh = kl + per;
    ushort_t* awh = vh + per;   // [MTOT][768] bf16 hi
    ushort_t* awl = awh + per;  // lo   (total 7*per*2 = 88 MB)

    dim3 blk(256);
    dim3 gproj(D_MODEL / 64, MTOT / 128);  // (12, 64)
    hipLaunchKernelGGL((gemm_f16<1>), gproj, blk, 0, stream, q_in, Wq, bq, qh, ql, SCALE_LOG2E);
    hipLaunchKernelGGL((gemm_f16<1>), gproj, blk, 0, stream, k_in, Wk, bk, kh, kl, 1.0f);
    hipLaunchKernelGGL((gemm_f16<2>), gproj, blk, 0, stream, v_in, Wv, bv, vh, nullptr, 1.0f);

    dim3 gattn(SEQ / 128, BATCH * NHEAD);  // (32, 24)
    hipLaunchKernelGGL(flash2, gattn, blk, 0, stream, qh, ql, kh, kl, vh, awh, awl);

    hipLaunchKernelGGL(gemm_osplit, gproj, blk, 0, stream, awh, awl, Wo, bo, out);
}

// Round 7
// 501.468 us; speedup vs baseline: 9.3804x; 1.5822x over previous
//
#include <hip/hip_runtime.h>
#include <cstdint>

#define D_MODEL 768
#define NHEAD 12
#define DK 64
#define BATCH 2
#define SEQ 4096
#define MTOT (BATCH * SEQ)  // 8192
#define NT (SEQ / 64)       // 64 K-tiles

typedef __attribute__((ext_vector_type(8))) _Float16 f16x8;  // 4 VGPRs
typedef __attribute__((ext_vector_type(4))) float f32x4;
typedef unsigned short ushort_t;

#define SCALE_LOG2E 0.18033688011112042f  // 0.125 * log2(e)
#define EXP2(d, s) asm("v_exp_f32 %0, %1" : "=v"(d) : "v"(s))

// XOR-swizzled byte offset in a row-major tile with 128B rows (64 f16/row)
__device__ __forceinline__ int swz(int row, int col_e) {
    return (row * 128 + col_e * 2) ^ ((row & 7) << 4);
}

// ================= fp16 MFMA GEMM: C = A @ W^T + bias =================
// BM=128, BN=64, BK=64; 256 thr = 4 waves (2x2).
// MODE 1: A fp32 [M][768] -> C fp16 head layout [B,H,S,DK], scaled by alpha
// MODE 0: A fp16 [M][768] -> C fp32 row-major [M][768]
template <int MODE>
__global__ __launch_bounds__(256) void gemm_f16(const void* __restrict__ Ap,
                                                const float* __restrict__ W,
                                                const float* __restrict__ bias,
                                                void* __restrict__ Cp,
                                                float alpha) {
    __shared__ __align__(16) char lds[24576];  // A 16KB @0, W 8KB @16384
    const int tid = threadIdx.x;
    const int lane = tid & 63;
    const int w = tid >> 6;
    const int li = lane & 15;
    const int g = lane >> 4;
    const int wr = w >> 1, wc = w & 1;
    const int m0 = blockIdx.y * 128;
    const int n0 = blockIdx.x * 64;

    f32x4 acc[4][2];
#pragma unroll
    for (int fr = 0; fr < 4; ++fr)
#pragma unroll
        for (int fc = 0; fc < 2; ++fc) acc[fr][fc] = (f32x4){0.f, 0.f, 0.f, 0.f};

    for (int k0 = 0; k0 < D_MODEL; k0 += 64) {
        __syncthreads();
        // ---- A tile 128x64 -> fp16 LDS
#pragma unroll
        for (int i = 0; i < 4; ++i) {
            const int c = tid + i * 256;
            const int row = c >> 3;
            const int c8 = (c & 7) * 8;
            if (MODE == 1) {
                const float* src = (const float*)Ap + (size_t)(m0 + row) * D_MODEL + k0 + c8;
                float4 f0 = *(const float4*)src;
                float4 f1 = *(const float4*)(src + 4);
                f16x8 h;
                h[0] = (_Float16)f0.x; h[1] = (_Float16)f0.y; h[2] = (_Float16)f0.z; h[3] = (_Float16)f0.w;
                h[4] = (_Float16)f1.x; h[5] = (_Float16)f1.y; h[6] = (_Float16)f1.z; h[7] = (_Float16)f1.w;
                *(f16x8*)(lds + swz(row, c8)) = h;
            } else {
                const ushort_t* src = (const ushort_t*)Ap + (size_t)(m0 + row) * D_MODEL + k0 + c8;
                *(f16x8*)(lds + swz(row, c8)) = *(const f16x8*)src;
            }
        }
        // ---- W tile 64x64 fp32 -> fp16 LDS
#pragma unroll
        for (int i = 0; i < 2; ++i) {
            const int c = tid + i * 256;
            const int row = c >> 3;
            const int c8 = (c & 7) * 8;
            const float* src = W + (size_t)(n0 + row) * D_MODEL + k0 + c8;
            float4 f0 = *(const float4*)src;
            float4 f1 = *(const float4*)(src + 4);
            f16x8 h;
            h[0] = (_Float16)f0.x; h[1] = (_Float16)f0.y; h[2] = (_Float16)f0.z; h[3] = (_Float16)f0.w;
            h[4] = (_Float16)f1.x; h[5] = (_Float16)f1.y; h[6] = (_Float16)f1.z; h[7] = (_Float16)f1.w;
            *(f16x8*)(lds + 16384 + swz(row, c8)) = h;
        }
        __syncthreads();
#pragma unroll
        for (int ks = 0; ks < 2; ++ks) {
            f16x8 ar[4], br[2];
#pragma unroll
            for (int fr = 0; fr < 4; ++fr)
                ar[fr] = *(const f16x8*)(lds + swz(wr * 64 + fr * 16 + li, ks * 32 + g * 8));
#pragma unroll
            for (int fc = 0; fc < 2; ++fc)
                br[fc] = *(const f16x8*)(lds + 16384 + swz(wc * 32 + fc * 16 + li, ks * 32 + g * 8));
#pragma unroll
            for (int fr = 0; fr < 4; ++fr)
#pragma unroll
                for (int fc = 0; fc < 2; ++fc)
                    acc[fr][fc] = __builtin_amdgcn_mfma_f32_16x16x32_f16(ar[fr], br[fc], acc[fr][fc], 0, 0, 0);
        }
    }

#pragma unroll
    for (int fr = 0; fr < 4; ++fr)
#pragma unroll
        for (int fc = 0; fc < 2; ++fc)
#pragma unroll
            for (int r = 0; r < 4; ++r) {
                const int m = m0 + wr * 64 + fr * 16 + g * 4 + r;
                const int d = wc * 32 + fc * 16 + li;
                float val = acc[fr][fc][r] + bias[n0 + d];
                if (MODE == 0) {
                    ((float*)Cp)[(size_t)m * D_MODEL + n0 + d] = val;
                } else {
                    val *= alpha;
                    const int b = m >> 12;
                    const int s = m & (SEQ - 1);
                    const size_t idx = (((size_t)b * NHEAD + blockIdx.x) * SEQ + s) * DK + d;
                    ((ushort_t*)Cp)[idx] = __builtin_bit_cast(ushort_t, (_Float16)val);
                }
            }
}

// ================= fp16 MFMA flash attention v3b =================
// Q (pre-scaled by 0.125*log2e), K, V fp16 in [B,H,S,DK].
// 4 waves; wave w owns q-rows [w*16, w*16+16). KBLK=64. T14 async-STAGE.
// V staged TRANSPOSED in LDS (Vt[d][k], R3-proven layout); PV B-frags via ds_read_b128.
// Output fp16 row-major [MTOT][768].
__global__ __launch_bounds__(256, 4) void flash3(const ushort_t* __restrict__ q_g,
                                                 const ushort_t* __restrict__ k_g,
                                                 const ushort_t* __restrict__ v_g,
                                                 ushort_t* __restrict__ aw) {
    __shared__ __align__(16) char lds[24576];
    constexpr int KH = 0, VT = 8192, PB = 16384;  // PB + w*2048

    const int tid = threadIdx.x;
    const int lane = tid & 63;
    const int w = tid >> 6;
    const int li = lane & 15;
    const int g = lane >> 4;
    const int bh = blockIdx.y;
    const int q0 = blockIdx.x * 64;

    const ushort_t* qp = q_g + (size_t)bh * SEQ * DK;
    const ushort_t* kp = k_g + (size_t)bh * SEQ * DK;
    const ushort_t* vp = v_g + (size_t)bh * SEQ * DK;

    // Q fragments straight from global (row w*16+li, cols ks*32+g*8)
    f16x8 qf[2];
#pragma unroll
    for (int ks = 0; ks < 2; ++ks)
        qf[ks] = *(const f16x8*)(qp + (size_t)(q0 + w * 16 + li) * DK + ks * 32 + g * 8);

    // K staging geometry: row = tid>>2 (0..63), c0 = (tid&3)*16
    const int srow = tid >> 2;
    const int sc0 = (tid & 3) * 16;
    const int kwr0 = KH + swz(srow, sc0);
    const int kwr1 = KH + swz(srow, sc0 + 8);
    // V staging: lane = d; wave w covers k rows [w*16, w*16+16) of the tile
    const int vd = lane;

    // prefetch tile 0
    f16x8 kst0, kst1;
    ushort4 vpk[4];
    {
        const ushort_t* ks_ = kp + (size_t)srow * DK + sc0;
        kst0 = *(const f16x8*)ks_;
        kst1 = *(const f16x8*)(ks_ + 8);
        const ushort_t* vs_ = vp + (size_t)(w * 16) * DK + vd;
#pragma unroll
        for (int j4 = 0; j4 < 4; ++j4) {
            vpk[j4].x = vs_[(j4 * 4 + 0) * DK];
            vpk[j4].y = vs_[(j4 * 4 + 1) * DK];
            vpk[j4].z = vs_[(j4 * 4 + 2) * DK];
            vpk[j4].w = vs_[(j4 * 4 + 3) * DK];
        }
    }

    f32x4 oacc[4];
    float m_r[4], l_r[4];
#pragma unroll
    for (int i = 0; i < 4; ++i) {
        oacc[i] = (f32x4){0.f, 0.f, 0.f, 0.f};
        m_r[i] = -1e30f;
        l_r[i] = 0.f;
    }

    const int pb = PB + w * 2048;

    for (int kt = 0; kt < NT; ++kt) {
        __syncthreads();  // all waves done reading previous K/V tiles
        *(f16x8*)(lds + kwr0) = kst0;
        *(f16x8*)(lds + kwr1) = kst1;
#pragma unroll
        for (int j4 = 0; j4 < 4; ++j4)
            *(ushort4*)(lds + VT + swz(vd, w * 16 + j4 * 4)) = vpk[j4];
        __syncthreads();  // K/V ready
        // T14: issue next tile's loads now; latency hides under this tile's compute
        if (kt + 1 < NT) {
            const ushort_t* ks_ = kp + (size_t)((kt + 1) * 64 + srow) * DK + sc0;
            kst0 = *(const f16x8*)ks_;
            kst1 = *(const f16x8*)(ks_ + 8);
            const ushort_t* vs_ = vp + (size_t)((kt + 1) * 64 + w * 16) * DK + vd;
#pragma unroll
            for (int j4 = 0; j4 < 4; ++j4) {
                vpk[j4].x = vs_[(j4 * 4 + 0) * DK];
                vpk[j4].y = vs_[(j4 * 4 + 1) * DK];
                vpk[j4].z = vs_[(j4 * 4 + 2) * DK];
                vpk[j4].w = vs_[(j4 * 4 + 3) * DK];
            }
        }

        // ---- S = Q K^T (fp16, log2-domain: scale pre-folded into Q)
        f32x4 sacc[4];
#pragma unroll
        for (int t = 0; t < 4; ++t) {
            sacc[t] = (f32x4){0.f, 0.f, 0.f, 0.f};
#pragma unroll
            for (int ks = 0; ks < 2; ++ks) {
                f16x8 kf = *(const f16x8*)(lds + KH + swz(t * 16 + li, ks * 32 + g * 8));
                sacc[t] = __builtin_amdgcn_mfma_f32_16x16x32_f16(qf[ks], kf, sacc[t], 0, 0, 0);
            }
        }

        // ---- online softmax (log2 domain), defer-max, lane-partial l
        float pm[4];
#pragma unroll
        for (int r = 0; r < 4; ++r) {
            float mx = fmaxf(fmaxf(sacc[0][r], sacc[1][r]), fmaxf(sacc[2][r], sacc[3][r]));
            mx = fmaxf(mx, __shfl_xor(mx, 1));
            mx = fmaxf(mx, __shfl_xor(mx, 2));
            mx = fmaxf(mx, __shfl_xor(mx, 4));
            mx = fmaxf(mx, __shfl_xor(mx, 8));
            pm[r] = mx;
        }
        bool need = false;
#pragma unroll
        for (int r = 0; r < 4; ++r) need = need || (pm[r] > m_r[r] + 8.0f);
        if (__any(need)) {
#pragma unroll
            for (int r = 0; r < 4; ++r) {
                const float mn = fmaxf(m_r[r], pm[r]);
                float corr;
                float dd = m_r[r] - mn;
                EXP2(corr, dd);
                m_r[r] = mn;
                l_r[r] *= corr;
#pragma unroll
                for (int dt = 0; dt < 4; ++dt) oacc[dt][r] *= corr;
            }
        }
#pragma unroll
        for (int r = 0; r < 4; ++r) {
            float p0, p1, p2, p3;
            float d0 = sacc[0][r] - m_r[r];
            float d1 = sacc[1][r] - m_r[r];
            float d2 = sacc[2][r] - m_r[r];
            float d3 = sacc[3][r] - m_r[r];
            EXP2(p0, d0); EXP2(p1, d1); EXP2(p2, d2); EXP2(p3, d3);
            l_r[r] += (p0 + p1) + (p2 + p3);  // lane-partial; reduced in epilogue
            const int prow = g * 4 + r;
            *(ushort_t*)(lds + pb + swz(prow, 0 * 16 + li)) = __builtin_bit_cast(ushort_t, (_Float16)p0);
            *(ushort_t*)(lds + pb + swz(prow, 1 * 16 + li)) = __builtin_bit_cast(ushort_t, (_Float16)p1);
            *(ushort_t*)(lds + pb + swz(prow, 2 * 16 + li)) = __builtin_bit_cast(ushort_t, (_Float16)p2);
            *(ushort_t*)(lds + pb + swz(prow, 3 * 16 + li)) = __builtin_bit_cast(ushort_t, (_Float16)p3);
        }

        // ---- O += P V : A = P [16x64] (wave-private), B frag from Vt via b128
        f16x8 pa[2];
#pragma unroll
        for (int ks = 0; ks < 2; ++ks)
            pa[ks] = *(const f16x8*)(lds + pb + swz(li, ks * 32 + g * 8));
#pragma unroll
        for (int dt = 0; dt < 4; ++dt)
#pragma unroll
            for (int ks = 0; ks < 2; ++ks) {
                f16x8 vf = *(const f16x8*)(lds + VT + swz(dt * 16 + li, ks * 32 + g * 8));
                oacc[dt] = __builtin_amdgcn_mfma_f32_16x16x32_f16(pa[ks], vf, oacc[dt], 0, 0, 0);
            }
    }

    // ---- epilogue: reduce lane-partial l across the 16 li-lanes, write fp16
    float inv[4];
#pragma unroll
    for (int r = 0; r < 4; ++r) {
        float lt = l_r[r];
        lt += __shfl_xor(lt, 1);
        lt += __shfl_xor(lt, 2);
        lt += __shfl_xor(lt, 4);
        lt += __shfl_xor(lt, 8);
        inv[r] = 1.0f / lt;
    }
    const int b = bh / NHEAD;
    const int hh = bh % NHEAD;
#pragma unroll
    for (int dt = 0; dt < 4; ++dt)
#pragma unroll
        for (int r = 0; r < 4; ++r) {
            const float val = oacc[dt][r] * inv[r];
            const int row = q0 + w * 16 + g * 4 + r;
            const size_t idx = ((size_t)b * SEQ + row) * D_MODEL + hh * DK + dt * 16 + li;
            aw[idx] = __builtin_bit_cast(ushort_t, (_Float16)val);
        }
}

extern "C" void kernel_launch(void* const* d_in, const int* in_sizes, int n_in,
                              void* d_out, int out_size, void* d_ws, size_t ws_size,
                              hipStream_t stream) {
    const float* q_in = (const float*)d_in[0];
    const float* k_in = (const float*)d_in[1];
    const float* v_in = (const float*)d_in[2];
    const float* Wq = (const float*)d_in[3];
    const float* bq = (const float*)d_in[4];
    const float* Wk = (const float*)d_in[5];
    const float* bk = (const float*)d_in[6];
    const float* Wv = (const float*)d_in[7];
    const float* bv = (const float*)d_in[8];
    const float* Wo = (const float*)d_in[9];
    const float* bo = (const float*)d_in[10];
    float* out = (float*)d_out;

    const size_t per = (size_t)BATCH * NHEAD * SEQ * DK;  // 6,291,456 elems
    ushort_t* qh = (ushort_t*)d_ws;
    ushort_t* kh = qh + per;
    ushort_t* vh = kh + per;
    ushort_t* aw = vh + per;  // [MTOT][768] fp16; total 4*per*2 = 50.3 MB

    dim3 blk(256);
    dim3 gproj(D_MODEL / 64, MTOT / 128);  // (12, 64)
    hipLaunchKernelGGL((gemm_f16<1>), gproj, blk, 0, stream, q_in, Wq, bq, qh, SCALE_LOG2E);
    hipLaunchKernelGGL((gemm_f16<1>), gproj, blk, 0, stream, k_in, Wk, bk, kh, 1.0f);
    hipLaunchKernelGGL((gemm_f16<1>), gproj, blk, 0, stream, v_in, Wv, bv, vh, 1.0f);

    dim3 gattn(SEQ / 64, BATCH * NHEAD);  // (64, 24)
    hipLaunchKernelGGL(flash3, gattn, blk, 0, stream, qh, kh, vh, aw);

    hipLaunchKernelGGL((gemm_f16<0>), gproj, blk, 0, stream, aw, Wo, bo, out, 1.0f);
}

// Round 8
// 411.486 us; speedup vs baseline: 11.4317x; 1.2187x over previous
//
#include <hip/hip_runtime.h>
#include <cstdint>

#define D_MODEL 768
#define NHEAD 12
#define DK 64
#define BATCH 2
#define SEQ 4096
#define MTOT (BATCH * SEQ)  // 8192
#define NT (SEQ / 64)       // 64 K-tiles
#define WSZ (D_MODEL * D_MODEL)

typedef __attribute__((ext_vector_type(8))) _Float16 f16x8;  // 4 VGPRs
typedef __attribute__((ext_vector_type(2))) _Float16 f16x2;
typedef __attribute__((ext_vector_type(4))) float f32x4;
typedef unsigned short ushort_t;
typedef unsigned int uint_t;

#define SCALE_LOG2E 0.18033688011112042f  // 0.125 * log2(e)
#define EXP2(d, s) asm("v_exp_f32 %0, %1" : "=v"(d) : "v"(s))

// XOR-swizzled byte offset in a row-major tile with 128B rows (64 f16/row)
__device__ __forceinline__ int swz(int row, int col_e) {
    return (row * 128 + col_e * 2) ^ ((row & 7) << 4);
}

__device__ __forceinline__ uint_t pkrtz(float a, float b) {
    return __builtin_bit_cast(uint_t, __builtin_amdgcn_cvt_pkrtz(a, b));
}

// ============ fp32 -> fp16 (RNE) bulk convert: 7 tensors in one launch ============
__global__ __launch_bounds__(256) void cvt7(const float* s0, const float* s1, const float* s2,
                                            const float* s3, const float* s4, const float* s5,
                                            const float* s6, ushort_t* d0, ushort_t* d1,
                                            ushort_t* d2, ushort_t* d3, ushort_t* d4,
                                            ushort_t* d5, ushort_t* d6) {
    const int t = blockIdx.y;
    const float* src;
    ushort_t* dst;
    int n;
    if (t == 0) { src = s0; dst = d0; n = MTOT * D_MODEL; }
    else if (t == 1) { src = s1; dst = d1; n = MTOT * D_MODEL; }
    else if (t == 2) { src = s2; dst = d2; n = MTOT * D_MODEL; }
    else if (t == 3) { src = s3; dst = d3; n = WSZ; }
    else if (t == 4) { src = s4; dst = d4; n = WSZ; }
    else if (t == 5) { src = s5; dst = d5; n = WSZ; }
    else { src = s6; dst = d6; n = WSZ; }
    const int i = (blockIdx.x * 256 + threadIdx.x) * 8;
    if (i >= n) return;
    float4 a = *(const float4*)(src + i);
    float4 b = *(const float4*)(src + i + 4);
    f16x8 h;  // RNE casts (same precision path as R7's in-loop staging)
    h[0] = (_Float16)a.x; h[1] = (_Float16)a.y; h[2] = (_Float16)a.z; h[3] = (_Float16)a.w;
    h[4] = (_Float16)b.x; h[5] = (_Float16)b.y; h[6] = (_Float16)b.z; h[7] = (_Float16)b.w;
    *(f16x8*)(dst + i) = h;
}

// ============ fp16 MFMA GEMM: C = A @ W^T + bias (A, W both fp16) ============
// BM=128, BN=64, BK=64; 256 thr = 4 waves (2x2).
// MODE 1: C fp16 head layout [B,H,S,DK], scaled by alpha
// MODE 0: C fp32 row-major [M][768]
template <int MODE>
__global__ __launch_bounds__(256) void gemm_f16(const ushort_t* __restrict__ Ap,
                                                const ushort_t* __restrict__ Wp,
                                                const float* __restrict__ bias,
                                                void* __restrict__ Cp,
                                                float alpha) {
    __shared__ __align__(16) char lds[24576];  // A 16KB @0, W 8KB @16384
    const int tid = threadIdx.x;
    const int lane = tid & 63;
    const int w = tid >> 6;
    const int li = lane & 15;
    const int g = lane >> 4;
    const int wr = w >> 1, wc = w & 1;
    const int m0 = blockIdx.y * 128;
    const int n0 = blockIdx.x * 64;

    f32x4 acc[4][2];
#pragma unroll
    for (int fr = 0; fr < 4; ++fr)
#pragma unroll
        for (int fc = 0; fc < 2; ++fc) acc[fr][fc] = (f32x4){0.f, 0.f, 0.f, 0.f};

    for (int k0 = 0; k0 < D_MODEL; k0 += 64) {
        __syncthreads();
        // ---- A tile 128x64 f16 -> LDS (pure vector copy, no cvt)
#pragma unroll
        for (int i = 0; i < 4; ++i) {
            const int c = tid + i * 256;
            const int row = c >> 3;
            const int c8 = (c & 7) * 8;
            *(f16x8*)(lds + swz(row, c8)) =
                *(const f16x8*)(Ap + (size_t)(m0 + row) * D_MODEL + k0 + c8);
        }
        // ---- W tile 64x64 f16 -> LDS
#pragma unroll
        for (int i = 0; i < 2; ++i) {
            const int c = tid + i * 256;
            const int row = c >> 3;
            const int c8 = (c & 7) * 8;
            *(f16x8*)(lds + 16384 + swz(row, c8)) =
                *(const f16x8*)(Wp + (size_t)(n0 + row) * D_MODEL + k0 + c8);
        }
        __syncthreads();
#pragma unroll
        for (int ks = 0; ks < 2; ++ks) {
            f16x8 ar[4], br[2];
#pragma unroll
            for (int fr = 0; fr < 4; ++fr)
                ar[fr] = *(const f16x8*)(lds + swz(wr * 64 + fr * 16 + li, ks * 32 + g * 8));
#pragma unroll
            for (int fc = 0; fc < 2; ++fc)
                br[fc] = *(const f16x8*)(lds + 16384 + swz(wc * 32 + fc * 16 + li, ks * 32 + g * 8));
#pragma unroll
            for (int fr = 0; fr < 4; ++fr)
#pragma unroll
                for (int fc = 0; fc < 2; ++fc)
                    acc[fr][fc] = __builtin_amdgcn_mfma_f32_16x16x32_f16(ar[fr], br[fc], acc[fr][fc], 0, 0, 0);
        }
    }

#pragma unroll
    for (int fr = 0; fr < 4; ++fr)
#pragma unroll
        for (int fc = 0; fc < 2; ++fc)
#pragma unroll
            for (int r = 0; r < 4; ++r) {
                const int m = m0 + wr * 64 + fr * 16 + g * 4 + r;
                const int d = wc * 32 + fc * 16 + li;
                float val = acc[fr][fc][r] + bias[n0 + d];
                if (MODE == 0) {
                    ((float*)Cp)[(size_t)m * D_MODEL + n0 + d] = val;
                } else {
                    val *= alpha;
                    const int b = m >> 12;
                    const int s = m & (SEQ - 1);
                    const size_t idx = (((size_t)b * NHEAD + blockIdx.x) * SEQ + s) * DK + d;
                    ((ushort_t*)Cp)[idx] = __builtin_bit_cast(ushort_t, (_Float16)val);
                }
            }
}

// ============ fp16 MFMA flash attention v4 ============
// Swapped QK^T (S^T = mfma(K, Q)): each lane owns ONE query (w*16+li) and 16
// key-scores in-register -> in-lane softmax + 2 shfl. K/V LDS double-buffered,
// ONE barrier per tile. V transposed in LDS (Vt[d][k], proven layout).
// PV: O^T = mfma(Vt-frag, P-frag). Output fp16 row-major [MTOT][768].
__global__ __launch_bounds__(256, 4) void flash4(const ushort_t* __restrict__ q_g,
                                                 const ushort_t* __restrict__ k_g,
                                                 const ushort_t* __restrict__ v_g,
                                                 ushort_t* __restrict__ aw) {
    __shared__ __align__(16) char lds[40960];
    // K: 0 / 8192 (dbuf), Vt: 16384 / 24576 (dbuf), P: 32768 + w*2048

    const int tid = threadIdx.x;
    const int lane = tid & 63;
    const int w = tid >> 6;
    const int li = lane & 15;
    const int g = lane >> 4;
    const int bh = blockIdx.y;
    const int q0 = blockIdx.x * 64;

    const ushort_t* qp = q_g + (size_t)bh * SEQ * DK;
    const ushort_t* kp = k_g + (size_t)bh * SEQ * DK;
    const ushort_t* vp = v_g + (size_t)bh * SEQ * DK;

    // Q fragments straight from global (row w*16+li, cols ks*32+g*8)
    f16x8 qf[2];
#pragma unroll
    for (int ks = 0; ks < 2; ++ks)
        qf[ks] = *(const f16x8*)(qp + (size_t)(q0 + w * 16 + li) * DK + ks * 32 + g * 8);

    // K staging: row = tid>>2, c0 = (tid&3)*16 ; V staging: lane = d column
    const int srow = tid >> 2;
    const int sc0 = (tid & 3) * 16;
    const int kwr0 = swz(srow, sc0);
    const int kwr1 = swz(srow, sc0 + 8);
    const int vd = lane;

    // double prefetch register sets
    f16x8 kpre[2][2];
    ushort4 vpre[2][4];
    {
        const ushort_t* ks_ = kp + (size_t)srow * DK + sc0;
        kpre[0][0] = *(const f16x8*)ks_;
        kpre[0][1] = *(const f16x8*)(ks_ + 8);
        const ushort_t* vs_ = vp + (size_t)(w * 16) * DK + vd;
#pragma unroll
        for (int j4 = 0; j4 < 4; ++j4) {
            vpre[0][j4].x = vs_[(j4 * 4 + 0) * DK];
            vpre[0][j4].y = vs_[(j4 * 4 + 1) * DK];
            vpre[0][j4].z = vs_[(j4 * 4 + 2) * DK];
            vpre[0][j4].w = vs_[(j4 * 4 + 3) * DK];
        }
    }

    f32x4 oacc[4];
#pragma unroll
    for (int i = 0; i < 4; ++i) oacc[i] = (f32x4){0.f, 0.f, 0.f, 0.f};
    float m_r = -1e30f, l_r = 0.f;  // per-lane scalars: one query per lane

    const int pb = 32768 + w * 2048;

    for (int kt2 = 0; kt2 < NT / 2; ++kt2) {
#pragma unroll
        for (int ph = 0; ph < 2; ++ph) {  // unrolled -> all indices static
            const int kt = kt2 * 2 + ph;
            const int KB = ph ? 8192 : 0;
            const int VB = ph ? 24576 : 16384;

            // write prefetched tile kt into buffer ph (nobody reads it: WAR safe
            // because its previous readers finished before barrier of tile kt-1)
            *(f16x8*)(lds + KB + kwr0) = kpre[ph][0];
            *(f16x8*)(lds + KB + kwr1) = kpre[ph][1];
#pragma unroll
            for (int j4 = 0; j4 < 4; ++j4)
                *(ushort4*)(lds + VB + swz(vd, w * 16 + j4 * 4)) = vpre[ph][j4];
            __syncthreads();  // the ONE barrier per tile: buf[ph] ready

            // T14: prefetch tile kt+1 into the other reg set
            if (kt + 1 < NT) {
                const ushort_t* ks_ = kp + (size_t)((kt + 1) * 64 + srow) * DK + sc0;
                kpre[ph ^ 1][0] = *(const f16x8*)ks_;
                kpre[ph ^ 1][1] = *(const f16x8*)(ks_ + 8);
                const ushort_t* vs_ = vp + (size_t)((kt + 1) * 64 + w * 16) * DK + vd;
#pragma unroll
                for (int j4 = 0; j4 < 4; ++j4) {
                    vpre[ph ^ 1][j4].x = vs_[(j4 * 4 + 0) * DK];
                    vpre[ph ^ 1][j4].y = vs_[(j4 * 4 + 1) * DK];
                    vpre[ph ^ 1][j4].z = vs_[(j4 * 4 + 2) * DK];
                    vpre[ph ^ 1][j4].w = vs_[(j4 * 4 + 3) * DK];
                }
            }

            // ---- S^T = mfma(K, Q): lane (g,li) holds S[q=w*16+li][k=t*16+g*4+r]
            f32x4 sacc[4];
#pragma unroll
            for (int t = 0; t < 4; ++t) {
                sacc[t] = (f32x4){0.f, 0.f, 0.f, 0.f};
#pragma unroll
                for (int ks = 0; ks < 2; ++ks) {
                    f16x8 kf = *(const f16x8*)(lds + KB + swz(t * 16 + li, ks * 32 + g * 8));
                    sacc[t] = __builtin_amdgcn_mfma_f32_16x16x32_f16(kf, qf[ks], sacc[t], 0, 0, 0);
                }
            }

            // ---- softmax (log2 domain): in-lane max over 16, 2 shfl across g
            float t0 = fmaxf(fmaxf(sacc[0][0], sacc[0][1]), fmaxf(sacc[0][2], sacc[0][3]));
            float t1 = fmaxf(fmaxf(sacc[1][0], sacc[1][1]), fmaxf(sacc[1][2], sacc[1][3]));
            float t2 = fmaxf(fmaxf(sacc[2][0], sacc[2][1]), fmaxf(sacc[2][2], sacc[2][3]));
            float t3 = fmaxf(fmaxf(sacc[3][0], sacc[3][1]), fmaxf(sacc[3][2], sacc[3][3]));
            float mx = fmaxf(fmaxf(t0, t1), fmaxf(t2, t3));
            mx = fmaxf(mx, __shfl_xor(mx, 16));
            mx = fmaxf(mx, __shfl_xor(mx, 32));

            if (__any(mx > m_r + 8.0f)) {  // defer-max (T13)
                const float nm = fmaxf(m_r, mx);
                float corr;
                float dd = m_r - nm;
                EXP2(corr, dd);
                m_r = nm;
                l_r *= corr;
#pragma unroll
                for (int dt = 0; dt < 4; ++dt) oacc[dt] *= corr;
            }

            // ---- P = exp2(S - m), pack to fp16, wave-private LDS row q=li
#pragma unroll
            for (int t = 0; t < 4; ++t) {
                float p0, p1, p2, p3;
                float e0 = sacc[t][0] - m_r;
                float e1 = sacc[t][1] - m_r;
                float e2 = sacc[t][2] - m_r;
                float e3 = sacc[t][3] - m_r;
                EXP2(p0, e0); EXP2(p1, e1); EXP2(p2, e2); EXP2(p3, e3);
                l_r += (p0 + p1) + (p2 + p3);  // lane-partial; reduced in epilogue
                uint2 pk;
                pk.x = pkrtz(p0, p1);
                pk.y = pkrtz(p2, p3);
                *(uint2*)(lds + pb + swz(li, t * 16 + g * 4)) = pk;
            }

            // ---- O^T += mfma(Vt-frag, P-frag)
            f16x8 pbf[2];
#pragma unroll
            for (int ks = 0; ks < 2; ++ks)
                pbf[ks] = *(const f16x8*)(lds + pb + swz(li, ks * 32 + g * 8));
#pragma unroll
            for (int dt = 0; dt < 4; ++dt)
#pragma unroll
                for (int ks = 0; ks < 2; ++ks) {
                    f16x8 vf = *(const f16x8*)(lds + VB + swz(dt * 16 + li, ks * 32 + g * 8));
                    oacc[dt] = __builtin_amdgcn_mfma_f32_16x16x32_f16(vf, pbf[ks], oacc[dt], 0, 0, 0);
                }
        }
    }

    // ---- epilogue: O^T layout -> lane owns row q, 4 consecutive d per dt
    float lt = l_r;
    lt += __shfl_xor(lt, 16);
    lt += __shfl_xor(lt, 32);
    const float inv = 1.0f / lt;
    const int b = bh / NHEAD;
    const int hh = bh % NHEAD;
    const int qrow = q0 + w * 16 + li;
#pragma unroll
    for (int dt = 0; dt < 4; ++dt) {
        uint2 o;
        o.x = pkrtz(oacc[dt][0] * inv, oacc[dt][1] * inv);
        o.y = pkrtz(oacc[dt][2] * inv, oacc[dt][3] * inv);
        *(uint2*)&aw[((size_t)b * SEQ + qrow) * D_MODEL + hh * DK + dt * 16 + g * 4] = o;
    }
}

extern "C" void kernel_launch(void* const* d_in, const int* in_sizes, int n_in,
                              void* d_out, int out_size, void* d_ws, size_t ws_size,
                              hipStream_t stream) {
    const float* q_in = (const float*)d_in[0];
    const float* k_in = (const float*)d_in[1];
    const float* v_in = (const float*)d_in[2];
    const float* Wq = (const float*)d_in[3];
    const float* bq = (const float*)d_in[4];
    const float* Wk = (const float*)d_in[5];
    const float* bk = (const float*)d_in[6];
    const float* Wv = (const float*)d_in[7];
    const float* bv = (const float*)d_in[8];
    const float* Wo = (const float*)d_in[9];
    const float* bo = (const float*)d_in[10];
    float* out = (float*)d_out;

    const size_t per = (size_t)MTOT * D_MODEL;  // 6,291,456 elems
    ushort_t* x16q = (ushort_t*)d_ws;
    ushort_t* x16k = x16q + per;
    ushort_t* x16v = x16k + per;
    ushort_t* w16 = x16v + per;     // 4 x WSZ (Wq, Wk, Wv, Wo)
    ushort_t* qh = w16 + 4 * (size_t)WSZ;
    ushort_t* kh = qh + per;
    ushort_t* vh = kh + per;
    ushort_t* aw = vh + per;  // total ~93 MB

    dim3 blk(256);
    dim3 gcvt(MTOT * D_MODEL / (256 * 8), 7);  // (3072, 7)
    hipLaunchKernelGGL(cvt7, gcvt, blk, 0, stream, q_in, k_in, v_in, Wq, Wk, Wv, Wo,
                       x16q, x16k, x16v, w16, w16 + WSZ, w16 + 2 * WSZ, w16 + 3 * WSZ);

    dim3 gproj(D_MODEL / 64, MTOT / 128);  // (12, 64)
    hipLaunchKernelGGL((gemm_f16<1>), gproj, blk, 0, stream, x16q, w16, bq, qh, SCALE_LOG2E);
    hipLaunchKernelGGL((gemm_f16<1>), gproj, blk, 0, stream, x16k, w16 + WSZ, bk, kh, 1.0f);
    hipLaunchKernelGGL((gemm_f16<1>), gproj, blk, 0, stream, x16v, w16 + 2 * WSZ, bv, vh, 1.0f);

    dim3 gattn(SEQ / 64, BATCH * NHEAD);  // (64, 24)
    hipLaunchKernelGGL(flash4, gattn, blk, 0, stream, qh, kh, vh, aw);

    hipLaunchKernelGGL((gemm_f16<0>), gproj, blk, 0, stream, aw, w16 + 3 * WSZ, bo, out, 1.0f);
}

// Round 9
// 374.584 us; speedup vs baseline: 12.5579x; 1.0985x over previous
//
#include <hip/hip_runtime.h>
#include <cstdint>

#define D_MODEL 768
#define NHEAD 12
#define DK 64
#define BATCH 2
#define SEQ 4096
#define MTOT (BATCH * SEQ)  // 8192
#define NT (SEQ / 64)       // 64 K-tiles
#define WSZ (D_MODEL * D_MODEL)

typedef __attribute__((ext_vector_type(8))) _Float16 f16x8;  // 4 VGPRs
typedef __attribute__((ext_vector_type(4))) float f32x4;
typedef unsigned short ushort_t;
typedef unsigned int uint_t;

#define SCALE_LOG2E 0.18033688011112042f  // 0.125 * log2(e)
#define EXP2(d, s) asm("v_exp_f32 %0, %1" : "=v"(d) : "v"(s))

// XOR-swizzled byte offset in a row-major tile with 128B rows (64 f16/row)
__device__ __forceinline__ int swz(int row, int col_e) {
    return (row * 128 + col_e * 2) ^ ((row & 7) << 4);
}

__device__ __forceinline__ uint_t pkrtz(float a, float b) {
    return __builtin_bit_cast(uint_t, __builtin_amdgcn_cvt_pkrtz(a, b));
}

// global -> LDS direct copy, 16B per lane. LDS dest = wave-uniform base + lane*16
// (linear). Source is PRE-SWIZZLED per lane so LDS content lands XOR-swizzled
// (rule #21: inverse-swz source + linear dest + swz read; XOR is an involution).
__device__ __forceinline__ void gl_lds16(const ushort_t* g, char* l) {
    __builtin_amdgcn_global_load_lds((const __attribute__((address_space(1))) void*)g,
                                     (__attribute__((address_space(3))) void*)l, 16, 0, 0);
}

// ============ fp32 -> fp16 (RNE) bulk convert: 7 tensors in one launch ============
__global__ __launch_bounds__(256) void cvt7(const float* s0, const float* s1, const float* s2,
                                            const float* s3, const float* s4, const float* s5,
                                            const float* s6, ushort_t* d0, ushort_t* d1,
                                            ushort_t* d2, ushort_t* d3, ushort_t* d4,
                                            ushort_t* d5, ushort_t* d6) {
    const int t = blockIdx.y;
    const float* src;
    ushort_t* dst;
    int n;
    if (t == 0) { src = s0; dst = d0; n = MTOT * D_MODEL; }
    else if (t == 1) { src = s1; dst = d1; n = MTOT * D_MODEL; }
    else if (t == 2) { src = s2; dst = d2; n = MTOT * D_MODEL; }
    else if (t == 3) { src = s3; dst = d3; n = WSZ; }
    else if (t == 4) { src = s4; dst = d4; n = WSZ; }
    else if (t == 5) { src = s5; dst = d5; n = WSZ; }
    else { src = s6; dst = d6; n = WSZ; }
    const int i = (blockIdx.x * 256 + threadIdx.x) * 8;
    if (i >= n) return;
    float4 a = *(const float4*)(src + i);
    float4 b = *(const float4*)(src + i + 4);
    f16x8 h;  // RNE casts
    h[0] = (_Float16)a.x; h[1] = (_Float16)a.y; h[2] = (_Float16)a.z; h[3] = (_Float16)a.w;
    h[4] = (_Float16)b.x; h[5] = (_Float16)b.y; h[6] = (_Float16)b.z; h[7] = (_Float16)b.w;
    *(f16x8*)(dst + i) = h;
}

// ============ staging for gemm: A-tile 128x64 f16 + W-tile 64x64 f16 via gload_lds ============
// Per wave: 4 instrs (A) + 2 instrs (W), each 1 KB (8 rows x 128 B).
// Lane l covers row chunk_base + (l>>3), source col byte ((l&7)*16)^((l>>3)<<4)
// (row&7 == l>>3 since all chunk bases are multiples of 8).
__device__ __forceinline__ void stage_gemm(const ushort_t* __restrict__ Ap,
                                           const ushort_t* __restrict__ Wp,
                                           int m0, int n0, int k0, char* ldsbuf,
                                           int w, int lane) {
    const int r8 = lane >> 3;
    const int cole = (((lane & 7) * 16) ^ (r8 << 4)) >> 1;  // pre-swz col in elems
#pragma unroll
    for (int j = 0; j < 4; ++j)
        gl_lds16(Ap + (size_t)(m0 + w * 32 + j * 8 + r8) * D_MODEL + k0 + cole,
                 ldsbuf + w * 4096 + j * 1024);
#pragma unroll
    for (int j = 0; j < 2; ++j)
        gl_lds16(Wp + (size_t)(n0 + w * 16 + j * 8 + r8) * D_MODEL + k0 + cole,
                 ldsbuf + 16384 + w * 2048 + j * 1024);
}

// ============ fp16 MFMA GEMM: C = A @ W^T + bias (A, W both fp16) ============
// BM=128, BN=64, BK=64; 256 thr = 4 waves (2x2). LDS double-buffered (2x24KB),
// ONE barrier per k-iter, staging via global_load_lds overlapping MFMA (T3 minimum).
// MODE 1: C fp16 head layout [B,H,S,DK], scaled by alpha
// MODE 0: C fp32 row-major [M][768]
template <int MODE>
__global__ __launch_bounds__(256) void gemm_f16(const ushort_t* __restrict__ Ap,
                                                const ushort_t* __restrict__ Wp,
                                                const float* __restrict__ bias,
                                                void* __restrict__ Cp,
                                                float alpha) {
    __shared__ __align__(16) char lds[49152];  // buf0 @0, buf1 @24576 (A 16K + W 8K each)
    const int tid = threadIdx.x;
    const int lane = tid & 63;
    const int w = tid >> 6;
    const int li = lane & 15;
    const int g = lane >> 4;
    const int wr = w >> 1, wc = w & 1;
    const int m0 = blockIdx.y * 128;
    const int n0 = blockIdx.x * 64;

    f32x4 acc[4][2];
#pragma unroll
    for (int fr = 0; fr < 4; ++fr)
#pragma unroll
        for (int fc = 0; fc < 2; ++fc) acc[fr][fc] = (f32x4){0.f, 0.f, 0.f, 0.f};

    stage_gemm(Ap, Wp, m0, n0, 0, lds, w, lane);
    __syncthreads();  // drains vmcnt: buf0 ready

    for (int kk = 0; kk < 6; ++kk) {
#pragma unroll
        for (int ph = 0; ph < 2; ++ph) {
            const int it = kk * 2 + ph;  // 0..11
            char* cur = lds + (ph ? 24576 : 0);
            // stage next k-tile into the other buffer (overlaps this iter's MFMA)
            if (it + 1 < 12)
                stage_gemm(Ap, Wp, m0, n0, (it + 1) * 64, lds + (ph ? 0 : 24576), w, lane);
#pragma unroll
            for (int ks = 0; ks < 2; ++ks) {
                f16x8 ar[4], br[2];
#pragma unroll
                for (int fr = 0; fr < 4; ++fr)
                    ar[fr] = *(const f16x8*)(cur + swz(wr * 64 + fr * 16 + li, ks * 32 + g * 8));
#pragma unroll
                for (int fc = 0; fc < 2; ++fc)
                    br[fc] = *(const f16x8*)(cur + 16384 + swz(wc * 32 + fc * 16 + li, ks * 32 + g * 8));
#pragma unroll
                for (int fr = 0; fr < 4; ++fr)
#pragma unroll
                    for (int fc = 0; fc < 2; ++fc)
                        acc[fr][fc] = __builtin_amdgcn_mfma_f32_16x16x32_f16(ar[fr], br[fc], acc[fr][fc], 0, 0, 0);
            }
            if (it + 1 < 12) __syncthreads();  // the ONE barrier: drains next-buf loads + WAR
        }
    }

#pragma unroll
    for (int fr = 0; fr < 4; ++fr)
#pragma unroll
        for (int fc = 0; fc < 2; ++fc)
#pragma unroll
            for (int r = 0; r < 4; ++r) {
                const int m = m0 + wr * 64 + fr * 16 + g * 4 + r;
                const int d = wc * 32 + fc * 16 + li;
                float val = acc[fr][fc][r] + bias[n0 + d];
                if (MODE == 0) {
                    ((float*)Cp)[(size_t)m * D_MODEL + n0 + d] = val;
                } else {
                    val *= alpha;
                    const int b = m >> 12;
                    const int s = m & (SEQ - 1);
                    const size_t idx = (((size_t)b * NHEAD + blockIdx.x) * SEQ + s) * DK + d;
                    ((ushort_t*)Cp)[idx] = __builtin_bit_cast(ushort_t, (_Float16)val);
                }
            }
}

// ============ fp16 MFMA flash attention v5: 8-wave blocks ============
// Swapped QK^T (S^T = mfma(K,Q)): lane owns ONE query + 16 key-scores in-register.
// 512 thr = 8 waves; wave w owns q-rows [q0 + w*16, +16); QBLK=128/block, KBLK=64.
// K staged via ONE global_load_lds per wave (pre-swz source); V transposed via
// 8 scalar gathers/thread. K/V LDS double-buffered, ONE barrier per tile.
// Output fp16 row-major [MTOT][768].
__global__ __launch_bounds__(512, 4) void flash5(const ushort_t* __restrict__ q_g,
                                                 const ushort_t* __restrict__ k_g,
                                                 const ushort_t* __restrict__ v_g,
                                                 ushort_t* __restrict__ aw) {
    __shared__ __align__(16) char lds[49152];
    // Kbuf: 0 / 8192 ; Vtbuf: 16384 / 24576 ; P: 32768 + w*2048

    const int tid = threadIdx.x;  // 0..511
    const int lane = tid & 63;
    const int w = tid >> 6;       // 0..7
    const int li = lane & 15;
    const int g = lane >> 4;
    const int bh = blockIdx.y;
    const int q0 = blockIdx.x * 128;

    const ushort_t* qp = q_g + (size_t)bh * SEQ * DK;
    const ushort_t* kp = k_g + (size_t)bh * SEQ * DK;
    const ushort_t* vp = v_g + (size_t)bh * SEQ * DK;

    // Q fragments straight from global (row q0 + w*16 + li)
    f16x8 qf[2];
#pragma unroll
    for (int ks = 0; ks < 2; ++ks)
        qf[ks] = *(const f16x8*)(qp + (size_t)(q0 + w * 16 + li) * DK + ks * 32 + g * 8);

    // K gload geometry: wave w covers rows [w*8, w*8+8) of the tile, 1 KB = 1 instr.
    // lane l: row w*8 + (l>>3); pre-swz source col (row&7 == l>>3 since w*8 % 8 == 0)
    const int kr8 = lane >> 3;
    const int kcole = (((lane & 7) * 16) ^ (kr8 << 4)) >> 1;
    const ushort_t* ksrc = kp + (size_t)(w * 8 + kr8) * DK + kcole;
    char* const kdst0 = lds + 0 + w * 1024;
    char* const kdst1 = lds + 8192 + w * 1024;

    // V gather: lane = d column; wave w covers k rows [w*8, w*8+8) of the tile
    const int vd = lane;
    const ushort_t* vsrc = vp + (size_t)(w * 8) * DK + vd;
    const int vw0 = swz(vd, w * 8);      // Vt row = d, cols w*8..w*8+3
    const int vw1 = swz(vd, w * 8 + 4);  // cols w*8+4..w*8+7

    // ---- prologue: stage tile 0 into buffers 0
    gl_lds16(ksrc, kdst0);
    ushort_t vr[8];
#pragma unroll
    for (int j = 0; j < 8; ++j) vr[j] = vsrc[(size_t)j * DK];
    {
        ushort4 u0, u1;
        u0.x = vr[0]; u0.y = vr[1]; u0.z = vr[2]; u0.w = vr[3];
        u1.x = vr[4]; u1.y = vr[5]; u1.z = vr[6]; u1.w = vr[7];
        *(ushort4*)(lds + 16384 + vw0) = u0;
        *(ushort4*)(lds + 16384 + vw1) = u1;
    }
    __syncthreads();  // drains K gload + publishes V writes: buffers 0 ready

    f32x4 oacc[4];
#pragma unroll
    for (int i = 0; i < 4; ++i) oacc[i] = (f32x4){0.f, 0.f, 0.f, 0.f};
    float m_r = -1e30f, l_r = 0.f;  // per-lane scalars: one query per lane

    const int pb = 32768 + w * 2048;

    for (int kt2 = 0; kt2 < NT / 2; ++kt2) {
#pragma unroll
        for (int ph = 0; ph < 2; ++ph) {  // static indices
            const int kt = kt2 * 2 + ph;
            const int KBc = ph ? 8192 : 0;
            const int VBc = ph ? 24576 : 16384;
            const int VBn = ph ? 16384 : 24576;
            const bool pre = (kt + 1 < NT);

            // issue next tile's K gload (into other K buffer; its readers finished
            // before the last barrier) and V scalar gathers (into regs)
            if (pre) {
                gl_lds16(ksrc + (size_t)(kt + 1) * 64 * DK, ph ? kdst0 : kdst1);
#pragma unroll
                for (int j = 0; j < 8; ++j)
                    vr[j] = vsrc[((size_t)(kt + 1) * 64 + j) * DK];
            }

            // ---- S^T = mfma(K, Q): lane holds S[q=w*16+li][k=t*16+g*4+r]
            f32x4 sacc[4];
#pragma unroll
            for (int t = 0; t < 4; ++t) {
                sacc[t] = (f32x4){0.f, 0.f, 0.f, 0.f};
#pragma unroll
                for (int ks = 0; ks < 2; ++ks) {
                    f16x8 kf = *(const f16x8*)(lds + KBc + swz(t * 16 + li, ks * 32 + g * 8));
                    sacc[t] = __builtin_amdgcn_mfma_f32_16x16x32_f16(kf, qf[ks], sacc[t], 0, 0, 0);
                }
            }

            // ---- softmax (log2 domain): in-lane max over 16, 2 shfl across g
            float t0 = fmaxf(fmaxf(sacc[0][0], sacc[0][1]), fmaxf(sacc[0][2], sacc[0][3]));
            float t1 = fmaxf(fmaxf(sacc[1][0], sacc[1][1]), fmaxf(sacc[1][2], sacc[1][3]));
            float t2 = fmaxf(fmaxf(sacc[2][0], sacc[2][1]), fmaxf(sacc[2][2], sacc[2][3]));
            float t3 = fmaxf(fmaxf(sacc[3][0], sacc[3][1]), fmaxf(sacc[3][2], sacc[3][3]));
            float mx = fmaxf(fmaxf(t0, t1), fmaxf(t2, t3));
            mx = fmaxf(mx, __shfl_xor(mx, 16));
            mx = fmaxf(mx, __shfl_xor(mx, 32));

            if (__any(mx > m_r + 8.0f)) {  // defer-max (T13)
                const float nm = fmaxf(m_r, mx);
                float corr;
                float dd = m_r - nm;
                EXP2(corr, dd);
                m_r = nm;
                l_r *= corr;
#pragma unroll
                for (int dt = 0; dt < 4; ++dt) oacc[dt] *= corr;
            }

            // ---- P = exp2(S - m), pack fp16, wave-private LDS row q=li
#pragma unroll
            for (int t = 0; t < 4; ++t) {
                float p0, p1, p2, p3;
                float e0 = sacc[t][0] - m_r;
                float e1 = sacc[t][1] - m_r;
                float e2 = sacc[t][2] - m_r;
                float e3 = sacc[t][3] - m_r;
                EXP2(p0, e0); EXP2(p1, e1); EXP2(p2, e2); EXP2(p3, e3);
                l_r += (p0 + p1) + (p2 + p3);  // lane-partial; reduced in epilogue
                uint2 pk;
                pk.x = pkrtz(p0, p1);
                pk.y = pkrtz(p2, p3);
                *(uint2*)(lds + pb + swz(li, t * 16 + g * 4)) = pk;
            }

            // ---- O^T += mfma(Vt-frag, P-frag)
            f16x8 pbf[2];
#pragma unroll
            for (int ks = 0; ks < 2; ++ks)
                pbf[ks] = *(const f16x8*)(lds + pb + swz(li, ks * 32 + g * 8));
#pragma unroll
            for (int dt = 0; dt < 4; ++dt)
#pragma unroll
                for (int ks = 0; ks < 2; ++ks) {
                    f16x8 vf = *(const f16x8*)(lds + VBc + swz(dt * 16 + li, ks * 32 + g * 8));
                    oacc[dt] = __builtin_amdgcn_mfma_f32_16x16x32_f16(vf, pbf[ks], oacc[dt], 0, 0, 0);
                }

            // ---- write next V tile (other buffer; WAR safe: its readers were
            // tile kt-1, done before the last barrier), then the ONE barrier
            if (pre) {
                ushort4 u0, u1;
                u0.x = vr[0]; u0.y = vr[1]; u0.z = vr[2]; u0.w = vr[3];
                u1.x = vr[4]; u1.y = vr[5]; u1.z = vr[6]; u1.w = vr[7];
                *(ushort4*)(lds + VBn + vw0) = u0;
                *(ushort4*)(lds + VBn + vw1) = u1;
                __syncthreads();  // drains next-K gload + publishes next-V
            }
        }
    }

    // ---- epilogue: reduce lane-partial l across the 4 g-groups, write fp16
    float lt = l_r;
    lt += __shfl_xor(lt, 16);
    lt += __shfl_xor(lt, 32);
    const float inv = 1.0f / lt;
    const int b = bh / NHEAD;
    const int hh = bh % NHEAD;
    const int qrow = q0 + w * 16 + li;
#pragma unroll
    for (int dt = 0; dt < 4; ++dt) {
        uint2 o;
        o.x = pkrtz(oacc[dt][0] * inv, oacc[dt][1] * inv);
        o.y = pkrtz(oacc[dt][2] * inv, oacc[dt][3] * inv);
        *(uint2*)&aw[((size_t)b * SEQ + qrow) * D_MODEL + hh * DK + dt * 16 + g * 4] = o;
    }
}

extern "C" void kernel_launch(void* const* d_in, const int* in_sizes, int n_in,
                              void* d_out, int out_size, void* d_ws, size_t ws_size,
                              hipStream_t stream) {
    const float* q_in = (const float*)d_in[0];
    const float* k_in = (const float*)d_in[1];
    const float* v_in = (const float*)d_in[2];
    const float* Wq = (const float*)d_in[3];
    const float* bq = (const float*)d_in[4];
    const float* Wk = (const float*)d_in[5];
    const float* bk = (const float*)d_in[6];
    const float* Wv = (const float*)d_in[7];
    const float* bv = (const float*)d_in[8];
    const float* Wo = (const float*)d_in[9];
    const float* bo = (const float*)d_in[10];
    float* out = (float*)d_out;

    const size_t per = (size_t)MTOT * D_MODEL;  // 6,291,456 elems
    ushort_t* x16q = (ushort_t*)d_ws;
    ushort_t* x16k = x16q + per;
    ushort_t* x16v = x16k + per;
    ushort_t* w16 = x16v + per;  // 4 x WSZ (Wq, Wk, Wv, Wo)
    ushort_t* qh = w16 + 4 * (size_t)WSZ;
    ushort_t* kh = qh + per;
    ushort_t* vh = kh + per;
    ushort_t* aw = vh + per;  // total ~93 MB

    dim3 blk(256);
    dim3 gcvt(MTOT * D_MODEL / (256 * 8), 7);  // (3072, 7)
    hipLaunchKernelGGL(cvt7, gcvt, blk, 0, stream, q_in, k_in, v_in, Wq, Wk, Wv, Wo,
                       x16q, x16k, x16v, w16, w16 + WSZ, w16 + 2 * WSZ, w16 + 3 * WSZ);

    dim3 gproj(D_MODEL / 64, MTOT / 128);  // (12, 64)
    hipLaunchKernelGGL((gemm_f16<1>), gproj, blk, 0, stream, x16q, w16, bq, qh, SCALE_LOG2E);
    hipLaunchKernelGGL((gemm_f16<1>), gproj, blk, 0, stream, x16k, w16 + WSZ, bk, kh, 1.0f);
    hipLaunchKernelGGL((gemm_f16<1>), gproj, blk, 0, stream, x16v, w16 + 2 * WSZ, bv, vh, 1.0f);

    dim3 gattn(SEQ / 128, BATCH * NHEAD);  // (32, 24)
    hipLaunchKernelGGL(flash5, gattn, dim3(512), 0, stream, qh, kh, vh, aw);

    hipLaunchKernelGGL((gemm_f16<0>), gproj, blk, 0, stream, aw, w16 + 3 * WSZ, bo, out, 1.0f);
}